// Round 1
// baseline (248.388 us; speedup 1.0000x reference)
//
#include <hip/hip_runtime.h>

typedef __attribute__((ext_vector_type(8))) short short8;
typedef __attribute__((ext_vector_type(4))) float f32x4;

#define SEQ 2048
#define BAT 8
#define DIM 512
#define RSQRT_D 0.044194173824159216f  // 1/sqrt(512)

__device__ __forceinline__ unsigned short f2bf(float x) {
  union { float f; unsigned u; } v; v.f = x;
  unsigned r = (v.u + 0x7FFFu + ((v.u >> 16) & 1u)) >> 16;  // RNE
  return (unsigned short)r;
}

__device__ __forceinline__ unsigned char f2fp8(float x) {
  return (unsigned char)(__builtin_amdgcn_cvt_pk_fp8_f32(x, x, 0, false) & 0xFF);
}

// async 16B global -> LDS. lds base wave-uniform; HW adds lane*16.
__device__ __forceinline__ void gload_lds16(const void* g, void* lds_base) {
  __builtin_amdgcn_global_load_lds(
      (const __attribute__((address_space(1))) unsigned int*)g,
      (__attribute__((address_space(3))) unsigned int*)lds_base,
      16, 0, 0);
}

// ---------------------------------------------------------------------------
// Kernel 1: fused pack. blocks x<4096: transpose feats (S,B,D) f32 ->
// (B,S,D) bf16 + overlap dot (y = src/tgt). blocks >=4096: y==0 -> cast
// Wq/Wk -> bf16; y==1 -> pack xyz -> (B,S,4) f32. grid = (4352, 2).
// ---------------------------------------------------------------------------
__global__ __launch_bounds__(256) void k_pack(
    const float* __restrict__ src, const float* __restrict__ tgt,
    const float* __restrict__ Wc, const float* __restrict__ bc,
    const float* __restrict__ sxyz, const float* __restrict__ txyz,
    const float* __restrict__ Wq, const float* __restrict__ Wk,
    unsigned short* __restrict__ srcT, unsigned short* __restrict__ tgtT,
    float4* __restrict__ Vsrc, float4* __restrict__ Vtgt,
    unsigned short* __restrict__ Wqb, unsigned short* __restrict__ Wkb,
    float* __restrict__ out) {
  int which = blockIdx.y;
  if (blockIdx.x >= 4096) {
    int e = (blockIdx.x - 4096) * 256 + threadIdx.x;   // 0..65535
    if (which == 0) {
      int wsel = e >> 15, j = e & 32767;
      const float* wp = (wsel ? Wk : Wq) + (size_t)j * 8;
      unsigned short* o = wsel ? Wkb : Wqb;
      float4 f0 = *(const float4*)wp, f1 = *(const float4*)(wp + 4);
      uint4 pk;
      pk.x = (unsigned)f2bf(f0.x) | ((unsigned)f2bf(f0.y) << 16);
      pk.y = (unsigned)f2bf(f0.z) | ((unsigned)f2bf(f0.w) << 16);
      pk.z = (unsigned)f2bf(f1.x) | ((unsigned)f2bf(f1.y) << 16);
      pk.w = (unsigned)f2bf(f1.z) | ((unsigned)f2bf(f1.w) << 16);
      *(uint4*)(o + (size_t)j * 8) = pk;
    } else if (e < 32768) {
      int wsel = e >> 14, id = e & 16383;
      int s = id >> 3, b = id & 7;
      const float* xyz = (wsel ? txyz : sxyz) + (size_t)id * 3;
      float4 v = make_float4(xyz[0], xyz[1], xyz[2], 0.f);
      (wsel ? Vtgt : Vsrc)[b * SEQ + s] = v;
    }
    return;
  }
  int w = threadIdx.x >> 6, lane = threadIdx.x & 63;
  int row = blockIdx.x * 4 + w;            // row = s*B + b
  const float* in = (which ? tgt : src) + (size_t)row * DIM;
  unsigned short* T = which ? tgtT : srcT;
  int s = row >> 3, b = row & 7;

  const float4* in4 = (const float4*)in;
  float4 f0 = in4[lane * 2], f1 = in4[lane * 2 + 1];

  uint4 pk;
  pk.x = (unsigned)f2bf(f0.x) | ((unsigned)f2bf(f0.y) << 16);
  pk.y = (unsigned)f2bf(f0.z) | ((unsigned)f2bf(f0.w) << 16);
  pk.z = (unsigned)f2bf(f1.x) | ((unsigned)f2bf(f1.y) << 16);
  pk.w = (unsigned)f2bf(f1.z) | ((unsigned)f2bf(f1.w) << 16);
  *(uint4*)(T + ((size_t)(b * SEQ + s) * DIM + lane * 8)) = pk;

  const float4* wc4 = (const float4*)Wc;
  float4 w0 = wc4[lane * 2], w1 = wc4[lane * 2 + 1];
  float d = f0.x * w0.x + f0.y * w0.y + f0.z * w0.z + f0.w * w0.w +
            f1.x * w1.x + f1.y * w1.y + f1.z * w1.z + f1.w * w1.w;
  for (int o = 32; o; o >>= 1) d += __shfl_xor(d, o);
  if (lane == 0) {
    int base = which ? (SEQ * BAT * 6 + SEQ * BAT) : (SEQ * BAT * 6);
    out[base + row] = d + bc[0];
  }
}

// ---------------------------------------------------------------------------
// Kernel 2: projection GEMM, fp8-e4m3 output, UNSCALED (1/sqrt(D) in attn).
// Q linear; K with bank-free swizzle baked into the global byte layout:
//   byte (row,d) at row*512 + ((d>>3 ^ (row&15))<<3) + (d&7)
// XCD grouping: the 16 blocks (4 n x 4 z) sharing one m-tile are consecutive
// on one XCD (id%8) -> A-tile L2-fetched once per XCD; W L2-resident.
// grid = 2048 x 1D, block = 256.
// ---------------------------------------------------------------------------
__global__ __launch_bounds__(256) void k_proj(
    const unsigned short* __restrict__ srcT, const unsigned short* __restrict__ tgtT,
    const unsigned short* __restrict__ Wqb, const unsigned short* __restrict__ Wkb,
    const float* __restrict__ bq, const float* __restrict__ bk,
    unsigned char* __restrict__ Qsrc, unsigned char* __restrict__ Ktgt,
    unsigned char* __restrict__ Qtgt, unsigned char* __restrict__ Ksrc) {
  __shared__ __align__(16) char at[16384];   // 128 rows x 128B (64 bf16)
  __shared__ __align__(16) char bt[16384];
  int id = blockIdx.x;                 // 0..2047
  int x = id & 7, t = id >> 3;         // XCD = x (heuristic)
  int m = x * 16 + (t >> 4);           // 0..127, 16 consecutive blocks share m
  int inner = t & 15;
  int n = inner & 3, z = inner >> 2;
  bool isQ = (z == 0 || z == 2);
  const unsigned short* A = (z == 0 || z == 3) ? srcT : tgtT;
  const unsigned short* W = isQ ? Wqb : Wkb;
  const float* bias = isQ ? bq : bk;
  unsigned char* O = z == 0 ? Qsrc : z == 1 ? Ktgt : z == 2 ? Qtgt : Ksrc;

  int m0 = m * 128, n0 = n * 128;
  int tid = threadIdx.x, w = tid >> 6, lane = tid & 63;
  int ln = lane & 15, quad = lane >> 4;
  int moff = (w & 1) * 64, noff = (w >> 1) * 64;

  f32x4 acc[4][4];
  f32x4 zero = {0.f, 0.f, 0.f, 0.f};
  for (int mi = 0; mi < 4; ++mi)
    for (int ni = 0; ni < 4; ++ni) acc[mi][ni] = zero;

  for (int kb = 0; kb < DIM; kb += 64) {
    #pragma unroll
    for (int it = 0; it < 4; ++it) {
      int rbase = w * 32 + it * 8;
      int r = rbase + (lane >> 3);
      int c = (lane & 7) ^ (r & 7);
      gload_lds16(A + ((size_t)(m0 + r) * DIM + kb + c * 8), &at[rbase * 128]);
      gload_lds16(W + ((size_t)(n0 + r) * DIM + kb + c * 8), &bt[rbase * 128]);
    }
    __syncthreads();
    #pragma unroll
    for (int ks = 0; ks < 2; ++ks) {
      short8 afr[4], bfr[4];
      #pragma unroll
      for (int mi = 0; mi < 4; ++mi) {
        int r = moff + mi * 16 + ln;
        int p = (ks * 4 + quad) ^ (r & 7);
        afr[mi] = *(const short8*)(&at[r * 128 + p * 16]);
      }
      #pragma unroll
      for (int ni = 0; ni < 4; ++ni) {
        int r = noff + ni * 16 + ln;
        int p = (ks * 4 + quad) ^ (r & 7);
        bfr[ni] = *(const short8*)(&bt[r * 128 + p * 16]);
      }
      #pragma unroll
      for (int mi = 0; mi < 4; ++mi)
        #pragma unroll
        for (int ni = 0; ni < 4; ++ni)
          acc[mi][ni] = __builtin_amdgcn_mfma_f32_16x16x32_bf16(afr[mi], bfr[ni], acc[mi][ni], 0, 0, 0);
    }
    __syncthreads();
  }

  for (int ni = 0; ni < 4; ++ni) {
    int n_g = n0 + noff + ni * 16 + ln;
    float bv = bias[n_g];
    for (int mi = 0; mi < 4; ++mi) {
      int m_g = m0 + moff + mi * 16 + quad * 4;
      for (int r = 0; r < 4; ++r) {
        float v = acc[mi][ni][r] + bv;
        int row = m_g + r;
        size_t pos;
        if (isQ) pos = (size_t)row * DIM + n_g;
        else     pos = (size_t)row * DIM + ((((n_g >> 3) ^ (row & 15)) << 3) | (n_g & 7));
        O[pos] = f2fp8(v);
      }
    }
  }
}

// ---------------------------------------------------------------------------
// Kernel 3: flash attention, fp8 scores, split-K x4, no-max softmax, V-SoA.
// v6 change: DOUBLE-buffered 16 KB K-tile with prefetch-before-compute and a
// SINGLE __syncthreads per 32-key block (its implicit vmcnt(0) drain lands
// after the MFMA phase, hiding the L2 stage latency under compute; the same
// barrier proves all waves finished reading the compute buffer before the
// next iteration's prefetch overwrites it). setprio(1) around MFMA cluster
// (4 staggered blocks/CU -> the m191 +4-7% case). LDS 38.9 KB -> 4 blk/CU.
// grid = 2048, blk 256.
// ---------------------------------------------------------------------------
__global__ __launch_bounds__(256) void k_attn(
    const unsigned char* __restrict__ Qsrc, const unsigned char* __restrict__ Ktgt,
    const unsigned char* __restrict__ Qtgt, const unsigned char* __restrict__ Ksrc,
    const float4* __restrict__ Vsrc, const float4* __restrict__ Vtgt,
    const int* __restrict__ src_lens, const int* __restrict__ tgt_lens,
    float4* __restrict__ part) {
  __shared__ __align__(16) char klds[32768];   // 2 x (32 keys x 512 B), swizzled
  __shared__ float vx[512], vy[512], vz[512];
  int id = blockIdx.x;                 // 0..2047
  int x = id & 7, j = id >> 3;         // XCD = x (heuristic)
  int group = (j >> 7) * 8 + x;        // 0..15 = dir*8+b, one XCD per group
  int dir = group >> 3, b = group & 7;
  int inner = j & 127;
  int chunk = inner >> 5, qb = inner & 31;

  const unsigned char* Q = dir ? Qtgt : Qsrc;
  const unsigned char* K = dir ? Ksrc : Ktgt;
  const float4* V = dir ? Vsrc : Vtgt;
  int len = (dir ? src_lens : tgt_lens)[b];
  int k0g = chunk * 512;
  int kend = min(len, k0g + 512);      // len >= 1792 so kend > k0g always
  int nblk = (kend - k0g + 31) >> 5;

  int tid = threadIdx.x, w = tid >> 6, lane = tid & 63;
  int ln = lane & 15, quad = lane >> 4;
  int q0 = qb * 64 + w * 16;

  // stage V chunk (512 keys) to LDS as SoA (conflict-free reads)
  for (int i = tid; i < 512; i += 256) {
    float4 vv = V[b * SEQ + k0g + i];
    vx[i] = vv.x; vy[i] = vv.y; vz[i] = vv.z;
  }

  const unsigned char* kchunk = K + (size_t)(b * SEQ + k0g) * DIM;

  // prologue: stage k-block 0 into buffer 0 (identity copy; swizzle is
  // pre-baked in the global byte layout). wave w stages 4 KB.
  #pragma unroll
  for (int it = 0; it < 4; ++it) {
    int rp = w * 4 + it;               // 1 KB per slot
    gload_lds16(kchunk + rp * 1024 + lane * 16, &klds[rp * 1024]);
  }

  // Q fp8 A-frags, full D: 16 x 8 B = 32 VGPRs. A[m=ln][k=quad*8+j].
  long af[16];
  {
    const unsigned char* qrow = Q + (size_t)(b * SEQ + q0 + ln) * DIM + quad * 8;
    #pragma unroll
    for (int kk = 0; kk < 16; ++kk)
      af[kk] = *(const long*)(qrow + kk * 32);
  }

  float l_r[4], Ox[4], Oy[4], Oz[4];
  #pragma unroll
  for (int r = 0; r < 4; ++r) { l_r[r] = 0.f; Ox[r] = Oy[r] = Oz[r] = 0.f; }

  __syncthreads();                     // buffer0 + V staged (vmcnt drained)

  int cur = 0;
  for (int kb = 0; kb < nblk; ++kb) {
    // prefetch next k-block into the idle buffer (clamped on last iter:
    // harmless redundant stage, never computed).
    {
      int kn = min(kb + 1, nblk - 1);
      const unsigned char* nbase = kchunk + (size_t)kn * 32 * DIM;
      char* nlds = &klds[(cur ^ 1) * 16384];
      #pragma unroll
      for (int it = 0; it < 4; ++it) {
        int rp = w * 4 + it;
        gload_lds16(nbase + rp * 1024 + lane * 16, nlds + rp * 1024);
      }
    }

    const char* krow0 = &klds[cur * 16384] + ln * DIM;
    const char* krow1 = krow0 + 16 * DIM;

    f32x4 acc0 = {0.f, 0.f, 0.f, 0.f}, acc1 = {0.f, 0.f, 0.f, 0.f};
    __builtin_amdgcn_s_setprio(1);
    #pragma unroll
    for (int kk = 0; kk < 16; ++kk) {
      int pos = (((kk * 4 + quad) ^ ln) << 3);  // swizzled 8B granule
      long b0 = *(const long*)(krow0 + pos);
      long b1 = *(const long*)(krow1 + pos);
      acc0 = __builtin_amdgcn_mfma_f32_16x16x32_fp8_fp8(af[kk], b0, acc0, 0, 0, 0);
      acc1 = __builtin_amdgcn_mfma_f32_16x16x32_fp8_fp8(af[kk], b1, acc1, 0, 0, 0);
    }
    __builtin_amdgcn_s_setprio(0);

    int lk0 = kb * 32 + ln, lk1 = lk0 + 16;
    bool v0 = (k0g + lk0) < kend, v1 = (k0g + lk1) < kend;
    float Vx0 = vx[lk0], Vy0 = vy[lk0], Vz0 = vz[lk0];
    float Vx1 = vx[lk1], Vy1 = vy[lk1], Vz1 = vz[lk1];
    #pragma unroll
    for (int r = 0; r < 4; ++r) {
      float p0 = v0 ? __expf(acc0[r] * RSQRT_D) : 0.f;
      float p1 = v1 ? __expf(acc1[r] * RSQRT_D) : 0.f;
      l_r[r] += p0 + p1;
      Ox[r] += p0 * Vx0 + p1 * Vx1;
      Oy[r] += p0 * Vy0 + p1 * Vy1;
      Oz[r] += p0 * Vz0 + p1 * Vz1;
    }

    __syncthreads();   // waves done reading buf[cur]; prefetch (own vmcnt) drained
    cur ^= 1;
  }

  // reduce over the 16 key-lanes + partial write (C: col=ln, row=quad*4+r)
  #pragma unroll
  for (int r = 0; r < 4; ++r) {
    float v0 = l_r[r], v1 = Ox[r], v2 = Oy[r], v3 = Oz[r];
    #pragma unroll
    for (int o = 1; o < 16; o <<= 1) {
      v0 += __shfl_xor(v0, o);
      v1 += __shfl_xor(v1, o);
      v2 += __shfl_xor(v2, o);
      v3 += __shfl_xor(v3, o);
    }
    if (ln == 0) {
      int q = q0 + quad * 4 + r;
      part[((size_t)(dir * BAT + b) * 4 + chunk) * SEQ + q] =
          make_float4(v0, v1, v2, v3);
    }
  }
}

// ---------------------------------------------------------------------------
// Kernel 4: combine split-K partials.
// ---------------------------------------------------------------------------
__global__ __launch_bounds__(256) void k_attn_reduce(
    const float4* __restrict__ part, float* __restrict__ out) {
  int t = blockIdx.x * 256 + threadIdx.x;    // 0..32767
  int dir = t >> 14, rem = t & 16383, b = rem >> 11, q = rem & 2047;
  size_t base = ((size_t)(dir * BAT + b) * 4) * SEQ + q;
  float4 s0 = part[base];
  float4 s1 = part[base + SEQ];
  float4 s2 = part[base + 2 * SEQ];
  float4 s3 = part[base + 3 * SEQ];
  float inv = 1.f / (s0.x + s1.x + s2.x + s3.x);
  float* ob = out + (size_t)dir * (SEQ * BAT * 3) + ((size_t)q * BAT + b) * 3;
  ob[0] = (s0.y + s1.y + s2.y + s3.y) * inv;
  ob[1] = (s0.z + s1.z + s2.z + s3.z) * inv;
  ob[2] = (s0.w + s1.w + s2.w + s3.w) * inv;
}

// ---------------------------------------------------------------------------
extern "C" void kernel_launch(void* const* d_in, const int* in_sizes, int n_in,
                              void* d_out, int out_size, void* d_ws, size_t ws_size,
                              hipStream_t stream) {
  const float* src  = (const float*)d_in[0];
  const float* tgt  = (const float*)d_in[1];
  const float* sxyz = (const float*)d_in[2];
  const float* txyz = (const float*)d_in[3];
  const int* slens  = (const int*)d_in[4];
  const int* tlens  = (const int*)d_in[5];
  const float* Wq   = (const float*)d_in[6];
  const float* bq   = (const float*)d_in[7];
  const float* Wk   = (const float*)d_in[8];
  const float* bk   = (const float*)d_in[9];
  const float* Wc   = (const float*)d_in[10];
  const float* bc   = (const float*)d_in[11];
  float* out = (float*)d_out;

  char* ws = (char*)d_ws;
  size_t off = 0;
  auto carve = [&](size_t bytes) -> char* {
    char* p = ws + off;
    off += (bytes + 255) & ~(size_t)255;
    return p;
  };
  const size_t FEAT_BF  = (size_t)BAT * SEQ * DIM * 2;  // 16 MB bf16
  const size_t FEAT_FP8 = (size_t)BAT * SEQ * DIM;      // 8 MB fp8
  unsigned short* srcT = (unsigned short*)carve(FEAT_BF);
  unsigned short* tgtT = (unsigned short*)carve(FEAT_BF);
  unsigned char* Qsrc = (unsigned char*)carve(FEAT_FP8);
  unsigned char* Ktgt = (unsigned char*)carve(FEAT_FP8);
  unsigned char* Qtgt = (unsigned char*)carve(FEAT_FP8);
  unsigned char* Ksrc = (unsigned char*)carve(FEAT_FP8);
  unsigned short* Wqb  = (unsigned short*)carve((size_t)DIM * DIM * 2);
  unsigned short* Wkb  = (unsigned short*)carve((size_t)DIM * DIM * 2);
  float4* Vsrc = (float4*)carve((size_t)BAT * SEQ * 16);
  float4* Vtgt = (float4*)carve((size_t)BAT * SEQ * 16);
  // split-K partials (2 MB) aliased onto srcT (dead after k_proj).
  float4* part = (float4*)srcT;

  k_pack<<<dim3(4352, 2), 256, 0, stream>>>(src, tgt, Wc, bc, sxyz, txyz, Wq, Wk,
                                            srcT, tgtT, Vsrc, Vtgt, Wqb, Wkb, out);
  k_proj<<<dim3(2048), 256, 0, stream>>>(srcT, tgtT, Wqb, Wkb, bq, bk,
                                         Qsrc, Ktgt, Qtgt, Ksrc);
  k_attn<<<dim3(2048), 256, 0, stream>>>(Qsrc, Ktgt, Qtgt, Ksrc, Vsrc, Vtgt,
                                         slens, tlens, part);
  k_attn_reduce<<<dim3(128), 256, 0, stream>>>(part, out);
}

// Round 2
// 238.413 us; speedup vs baseline: 1.0418x; 1.0418x over previous
//
#include <hip/hip_runtime.h>

typedef __attribute__((ext_vector_type(8))) short short8;
typedef __attribute__((ext_vector_type(4))) short s16x4;
typedef __attribute__((ext_vector_type(4))) float f32x4;

#define SEQ 2048
#define BAT 8
#define DIM 512
#define RSQRT_D 0.044194173824159216f  // 1/sqrt(512)

__device__ __forceinline__ unsigned short f2bf(float x) {
  union { float f; unsigned u; } v; v.f = x;
  unsigned r = (v.u + 0x7FFFu + ((v.u >> 16) & 1u)) >> 16;  // RNE
  return (unsigned short)r;
}

__device__ __forceinline__ unsigned char f2fp8(float x) {
  return (unsigned char)(__builtin_amdgcn_cvt_pk_fp8_f32(x, x, 0, false) & 0xFF);
}

// async 16B global -> LDS. lds base wave-uniform; HW adds lane*16.
__device__ __forceinline__ void gload_lds16(const void* g, void* lds_base) {
  __builtin_amdgcn_global_load_lds(
      (const __attribute__((address_space(1))) unsigned int*)g,
      (__attribute__((address_space(3))) unsigned int*)lds_base,
      16, 0, 0);
}

// P.V via small bf16 MFMA (16x16x16: A=4 bf16, B=4 bf16, C=4 f32).
__device__ __forceinline__ f32x4 mfma_pv(s16x4 a, s16x4 b, f32x4 c) {
  asm("v_mfma_f32_16x16x16_bf16 %0, %1, %2, %0" : "+v"(c) : "v"(a), "v"(b));
  return c;
}

// ---------------------------------------------------------------------------
// Kernel 1: fused pack. blocks x<4096: transpose feats (S,B,D) f32 ->
// (B,S,D) bf16 + overlap dot (y = src/tgt). blocks >=4096: y==0 -> cast
// Wq/Wk -> bf16; y==1 -> pack xyz -> (B,S,4) f32. grid = (4352, 2).
// ---------------------------------------------------------------------------
__global__ __launch_bounds__(256) void k_pack(
    const float* __restrict__ src, const float* __restrict__ tgt,
    const float* __restrict__ Wc, const float* __restrict__ bc,
    const float* __restrict__ sxyz, const float* __restrict__ txyz,
    const float* __restrict__ Wq, const float* __restrict__ Wk,
    unsigned short* __restrict__ srcT, unsigned short* __restrict__ tgtT,
    float4* __restrict__ Vsrc, float4* __restrict__ Vtgt,
    unsigned short* __restrict__ Wqb, unsigned short* __restrict__ Wkb,
    float* __restrict__ out) {
  int which = blockIdx.y;
  if (blockIdx.x >= 4096) {
    int e = (blockIdx.x - 4096) * 256 + threadIdx.x;   // 0..65535
    if (which == 0) {
      int wsel = e >> 15, j = e & 32767;
      const float* wp = (wsel ? Wk : Wq) + (size_t)j * 8;
      unsigned short* o = wsel ? Wkb : Wqb;
      float4 f0 = *(const float4*)wp, f1 = *(const float4*)(wp + 4);
      uint4 pk;
      pk.x = (unsigned)f2bf(f0.x) | ((unsigned)f2bf(f0.y) << 16);
      pk.y = (unsigned)f2bf(f0.z) | ((unsigned)f2bf(f0.w) << 16);
      pk.z = (unsigned)f2bf(f1.x) | ((unsigned)f2bf(f1.y) << 16);
      pk.w = (unsigned)f2bf(f1.z) | ((unsigned)f2bf(f1.w) << 16);
      *(uint4*)(o + (size_t)j * 8) = pk;
    } else if (e < 32768) {
      int wsel = e >> 14, id = e & 16383;
      int s = id >> 3, b = id & 7;
      const float* xyz = (wsel ? txyz : sxyz) + (size_t)id * 3;
      float4 v = make_float4(xyz[0], xyz[1], xyz[2], 0.f);
      (wsel ? Vtgt : Vsrc)[b * SEQ + s] = v;
    }
    return;
  }
  int w = threadIdx.x >> 6, lane = threadIdx.x & 63;
  int row = blockIdx.x * 4 + w;            // row = s*B + b
  const float* in = (which ? tgt : src) + (size_t)row * DIM;
  unsigned short* T = which ? tgtT : srcT;
  int s = row >> 3, b = row & 7;

  const float4* in4 = (const float4*)in;
  float4 f0 = in4[lane * 2], f1 = in4[lane * 2 + 1];

  uint4 pk;
  pk.x = (unsigned)f2bf(f0.x) | ((unsigned)f2bf(f0.y) << 16);
  pk.y = (unsigned)f2bf(f0.z) | ((unsigned)f2bf(f0.w) << 16);
  pk.z = (unsigned)f2bf(f1.x) | ((unsigned)f2bf(f1.y) << 16);
  pk.w = (unsigned)f2bf(f1.z) | ((unsigned)f2bf(f1.w) << 16);
  *(uint4*)(T + ((size_t)(b * SEQ + s) * DIM + lane * 8)) = pk;

  const float4* wc4 = (const float4*)Wc;
  float4 w0 = wc4[lane * 2], w1 = wc4[lane * 2 + 1];
  float d = f0.x * w0.x + f0.y * w0.y + f0.z * w0.z + f0.w * w0.w +
            f1.x * w1.x + f1.y * w1.y + f1.z * w1.z + f1.w * w1.w;
  for (int o = 32; o; o >>= 1) d += __shfl_xor(d, o);
  if (lane == 0) {
    int base = which ? (SEQ * BAT * 6 + SEQ * BAT) : (SEQ * BAT * 6);
    out[base + row] = d + bc[0];
  }
}

// ---------------------------------------------------------------------------
// Kernel 2: projection GEMM, fp8-e4m3 output, UNSCALED (1/sqrt(D) in attn).
// Q linear; K with bank-free swizzle baked into the global byte layout:
//   byte (row,d) at row*512 + ((d>>3 ^ (row&15))<<3) + (d&7)
// XCD grouping: the 16 blocks (4 n x 4 z) sharing one m-tile are consecutive
// on one XCD (id%8) -> A-tile L2-fetched once per XCD; W L2-resident.
// grid = 2048 x 1D, block = 256.
// ---------------------------------------------------------------------------
__global__ __launch_bounds__(256) void k_proj(
    const unsigned short* __restrict__ srcT, const unsigned short* __restrict__ tgtT,
    const unsigned short* __restrict__ Wqb, const unsigned short* __restrict__ Wkb,
    const float* __restrict__ bq, const float* __restrict__ bk,
    unsigned char* __restrict__ Qsrc, unsigned char* __restrict__ Ktgt,
    unsigned char* __restrict__ Qtgt, unsigned char* __restrict__ Ksrc) {
  __shared__ __align__(16) char at[16384];   // 128 rows x 128B (64 bf16)
  __shared__ __align__(16) char bt[16384];
  int id = blockIdx.x;                 // 0..2047
  int x = id & 7, t = id >> 3;         // XCD = x (heuristic)
  int m = x * 16 + (t >> 4);           // 0..127, 16 consecutive blocks share m
  int inner = t & 15;
  int n = inner & 3, z = inner >> 2;
  bool isQ = (z == 0 || z == 2);
  const unsigned short* A = (z == 0 || z == 3) ? srcT : tgtT;
  const unsigned short* W = isQ ? Wqb : Wkb;
  const float* bias = isQ ? bq : bk;
  unsigned char* O = z == 0 ? Qsrc : z == 1 ? Ktgt : z == 2 ? Qtgt : Ksrc;

  int m0 = m * 128, n0 = n * 128;
  int tid = threadIdx.x, w = tid >> 6, lane = tid & 63;
  int ln = lane & 15, quad = lane >> 4;
  int moff = (w & 1) * 64, noff = (w >> 1) * 64;

  f32x4 acc[4][4];
  f32x4 zero = {0.f, 0.f, 0.f, 0.f};
  for (int mi = 0; mi < 4; ++mi)
    for (int ni = 0; ni < 4; ++ni) acc[mi][ni] = zero;

  for (int kb = 0; kb < DIM; kb += 64) {
    #pragma unroll
    for (int it = 0; it < 4; ++it) {
      int rbase = w * 32 + it * 8;
      int r = rbase + (lane >> 3);
      int c = (lane & 7) ^ (r & 7);
      gload_lds16(A + ((size_t)(m0 + r) * DIM + kb + c * 8), &at[rbase * 128]);
      gload_lds16(W + ((size_t)(n0 + r) * DIM + kb + c * 8), &bt[rbase * 128]);
    }
    __syncthreads();
    #pragma unroll
    for (int ks = 0; ks < 2; ++ks) {
      short8 afr[4], bfr[4];
      #pragma unroll
      for (int mi = 0; mi < 4; ++mi) {
        int r = moff + mi * 16 + ln;
        int p = (ks * 4 + quad) ^ (r & 7);
        afr[mi] = *(const short8*)(&at[r * 128 + p * 16]);
      }
      #pragma unroll
      for (int ni = 0; ni < 4; ++ni) {
        int r = noff + ni * 16 + ln;
        int p = (ks * 4 + quad) ^ (r & 7);
        bfr[ni] = *(const short8*)(&bt[r * 128 + p * 16]);
      }
      #pragma unroll
      for (int mi = 0; mi < 4; ++mi)
        #pragma unroll
        for (int ni = 0; ni < 4; ++ni)
          acc[mi][ni] = __builtin_amdgcn_mfma_f32_16x16x32_bf16(afr[mi], bfr[ni], acc[mi][ni], 0, 0, 0);
    }
    __syncthreads();
  }

  for (int ni = 0; ni < 4; ++ni) {
    int n_g = n0 + noff + ni * 16 + ln;
    float bv = bias[n_g];
    for (int mi = 0; mi < 4; ++mi) {
      int m_g = m0 + moff + mi * 16 + quad * 4;
      for (int r = 0; r < 4; ++r) {
        float v = acc[mi][ni][r] + bv;
        int row = m_g + r;
        size_t pos;
        if (isQ) pos = (size_t)row * DIM + n_g;
        else     pos = (size_t)row * DIM + ((((n_g >> 3) ^ (row & 15)) << 3) | (n_g & 7));
        O[pos] = f2fp8(v);
      }
    }
  }
}

// ---------------------------------------------------------------------------
// Kernel 3: flash attention, fp8 scores, split-K x4, no-max softmax.
// v7: revert to single-buffer 16 KB K-tile (round-1 dbuf regressed) and move
// the P.V contraction onto the matrix pipe:
//  - SWAPPED QK^T: mfma(K_frag, Q_frag) -> D[key=quad*4+r][q=ln]. Same LDS
//    reads, same Q regs (A/B per-lane layouts are identical), just transposed.
//  - P cvt to bf16 (4x v_cvt_pk_bf16_f32) is exactly the B-frag of
//    v_mfma_f32_16x16x16_bf16; A = Vaug[key][comp]=(valid,x,y,z) bf16 in LDS.
//    2 tiny MFMAs replace ~40 VALU P.V + masking + the 128-instr end reduce.
//  - masking exact via Vaug=0 rows (p*0=0); quad0 lanes hold (l,Ox,Oy,Oz).
// LDS 16K+4K=20480 -> 8 blocks/CU (entire grid resident). grid 2048, blk 256.
// ---------------------------------------------------------------------------
__global__ __launch_bounds__(256) void k_attn(
    const unsigned char* __restrict__ Qsrc, const unsigned char* __restrict__ Ktgt,
    const unsigned char* __restrict__ Qtgt, const unsigned char* __restrict__ Ksrc,
    const float4* __restrict__ Vsrc, const float4* __restrict__ Vtgt,
    const int* __restrict__ src_lens, const int* __restrict__ tgt_lens,
    float4* __restrict__ part) {
  __shared__ __align__(16) char klds[16384];   // 32 keys x 512 B, swizzled
  __shared__ __align__(16) char vaug[4096];    // [grp=key/4][comp=4][j=4] bf16
  int id = blockIdx.x;                 // 0..2047
  int x = id & 7, j = id >> 3;         // XCD = x (heuristic)
  int group = (j >> 7) * 8 + x;        // 0..15 = dir*8+b, one XCD per group
  int dir = group >> 3, b = group & 7;
  int inner = j & 127;
  int chunk = inner >> 5, qb = inner & 31;

  const unsigned char* Q = dir ? Qtgt : Qsrc;
  const unsigned char* K = dir ? Ksrc : Ktgt;
  const float4* V = dir ? Vsrc : Vtgt;
  int len = (dir ? src_lens : tgt_lens)[b];
  int k0g = chunk * 512;
  int kend = min(len, k0g + 512);      // len >= 1792 so kend > k0g always
  int nblk = (kend - k0g + 31) >> 5;

  int tid = threadIdx.x, w = tid >> 6, lane = tid & 63;
  int ln = lane & 15, quad = lane >> 4;
  int q0 = qb * 64 + w * 16;

  // build Vaug: grp g holds bf16 Vaug[comp in {1,x,y,z}][key=g*4+j], with
  // invalid keys (>= len) zeroed -> exact masking through the PV MFMA.
  if (tid < 128) {
    int rem = kend - k0g;              // valid keys in this chunk
    const float4* vsrc = V + b * SEQ + k0g + tid * 4;
    float c[4][4];
    #pragma unroll
    for (int jj = 0; jj < 4; ++jj) {
      float4 vv = vsrc[jj];
      bool val = (tid * 4 + jj) < rem;
      c[0][jj] = val ? 1.f : 0.f;
      c[1][jj] = val ? vv.x : 0.f;
      c[2][jj] = val ? vv.y : 0.f;
      c[3][jj] = val ? vv.z : 0.f;
    }
    uint4 w0, w1;
    w0.x = (unsigned)f2bf(c[0][0]) | ((unsigned)f2bf(c[0][1]) << 16);
    w0.y = (unsigned)f2bf(c[0][2]) | ((unsigned)f2bf(c[0][3]) << 16);
    w0.z = (unsigned)f2bf(c[1][0]) | ((unsigned)f2bf(c[1][1]) << 16);
    w0.w = (unsigned)f2bf(c[1][2]) | ((unsigned)f2bf(c[1][3]) << 16);
    w1.x = (unsigned)f2bf(c[2][0]) | ((unsigned)f2bf(c[2][1]) << 16);
    w1.y = (unsigned)f2bf(c[2][2]) | ((unsigned)f2bf(c[2][3]) << 16);
    w1.z = (unsigned)f2bf(c[3][0]) | ((unsigned)f2bf(c[3][1]) << 16);
    w1.w = (unsigned)f2bf(c[3][2]) | ((unsigned)f2bf(c[3][3]) << 16);
    *(uint4*)(vaug + tid * 32) = w0;
    *(uint4*)(vaug + tid * 32 + 16) = w1;
  }

  // Q fp8 frags, full D: 16 x 8 B = 32 VGPRs. Used as B: B[k=quad*8+j][n=ln].
  long af[16];
  {
    const unsigned char* qrow = Q + (size_t)(b * SEQ + q0 + ln) * DIM + quad * 8;
    #pragma unroll
    for (int kk = 0; kk < 16; ++kk)
      af[kk] = *(const long*)(qrow + kk * 32);
  }

  f32x4 accPV = {0.f, 0.f, 0.f, 0.f};   // rows(comp)=quad*4+r, col(q)=ln
  const unsigned char* kchunk = K + (size_t)(b * SEQ + k0g) * DIM;

  for (int kb = 0; kb < nblk; ++kb) {
    // stage 32 keys x 512 B = 16 KB (identity copy; swizzle pre-baked).
    const unsigned char* kbase = kchunk + (size_t)kb * 32 * DIM;
    #pragma unroll
    for (int it = 0; it < 4; ++it) {
      int rp = w * 4 + it;             // 1 KB per slot
      gload_lds16(kbase + rp * 1024 + lane * 16, &klds[rp * 1024]);
    }
    __syncthreads();                   // stage complete (covers vaug build too)

    const char* krow0 = klds + ln * DIM;
    const char* krow1 = krow0 + 16 * DIM;

    // swapped QK^T: D[m=key sub][n=q=ln]
    f32x4 acc0 = {0.f, 0.f, 0.f, 0.f}, acc1 = {0.f, 0.f, 0.f, 0.f};
    __builtin_amdgcn_s_setprio(1);
    #pragma unroll
    for (int kk = 0; kk < 16; ++kk) {
      int pos = (((kk * 4 + quad) ^ ln) << 3);  // swizzled 8B granule
      long b0 = *(const long*)(krow0 + pos);
      long b1 = *(const long*)(krow1 + pos);
      acc0 = __builtin_amdgcn_mfma_f32_16x16x32_fp8_fp8(b0, af[kk], acc0, 0, 0, 0);
      acc1 = __builtin_amdgcn_mfma_f32_16x16x32_fp8_fp8(b1, af[kk], acc1, 0, 0, 0);
    }
    __builtin_amdgcn_s_setprio(0);

    // softmax (no-max) -> bf16 P frags (B-layout of 16x16x16 mfma)
    unsigned u00, u01, u10, u11;
    {
      float p0 = __expf(acc0[0] * RSQRT_D), p1 = __expf(acc0[1] * RSQRT_D);
      float p2 = __expf(acc0[2] * RSQRT_D), p3 = __expf(acc0[3] * RSQRT_D);
      asm("v_cvt_pk_bf16_f32 %0, %1, %2" : "=v"(u00) : "v"(p0), "v"(p1));
      asm("v_cvt_pk_bf16_f32 %0, %1, %2" : "=v"(u01) : "v"(p2), "v"(p3));
      float r0 = __expf(acc1[0] * RSQRT_D), r1 = __expf(acc1[1] * RSQRT_D);
      float r2 = __expf(acc1[2] * RSQRT_D), r3 = __expf(acc1[3] * RSQRT_D);
      asm("v_cvt_pk_bf16_f32 %0, %1, %2" : "=v"(u10) : "v"(r0), "v"(r1));
      asm("v_cvt_pk_bf16_f32 %0, %1, %2" : "=v"(u11) : "v"(r2), "v"(r3));
    }
    union U { unsigned u[2]; s16x4 s; };
    U pb0; pb0.u[0] = u00; pb0.u[1] = u01;
    U pb1; pb1.u[0] = u10; pb1.u[1] = u11;

    // Vaug A-frags: lane reads comp=ln&3 (rows>=4 of A are don't-care: only
    // D rows 0..3 are consumed). 4-lane same-address broadcast, conflict-free.
    int voff = kb * 256 + quad * 32 + (ln & 3) * 8;
    s16x4 va0 = *(const s16x4*)(vaug + voff);
    s16x4 va1 = *(const s16x4*)(vaug + voff + 128);
    accPV = mfma_pv(va0, pb0.s, accPV);
    accPV = mfma_pv(va1, pb1.s, accPV);

    __syncthreads();                   // all waves done reading klds
  }

  // quad0 lanes hold (l, Ox, Oy, Oz) for q = q0 + ln. No shuffle reduce.
  if (quad == 0) {
    int q = q0 + ln;
    part[((size_t)(dir * BAT + b) * 4 + chunk) * SEQ + q] =
        make_float4(accPV[0], accPV[1], accPV[2], accPV[3]);
  }
}

// ---------------------------------------------------------------------------
// Kernel 4: combine split-K partials.
// ---------------------------------------------------------------------------
__global__ __launch_bounds__(256) void k_attn_reduce(
    const float4* __restrict__ part, float* __restrict__ out) {
  int t = blockIdx.x * 256 + threadIdx.x;    // 0..32767
  int dir = t >> 14, rem = t & 16383, b = rem >> 11, q = rem & 2047;
  size_t base = ((size_t)(dir * BAT + b) * 4) * SEQ + q;
  float4 s0 = part[base];
  float4 s1 = part[base + SEQ];
  float4 s2 = part[base + 2 * SEQ];
  float4 s3 = part[base + 3 * SEQ];
  float inv = 1.f / (s0.x + s1.x + s2.x + s3.x);
  float* ob = out + (size_t)dir * (SEQ * BAT * 3) + ((size_t)q * BAT + b) * 3;
  ob[0] = (s0.y + s1.y + s2.y + s3.y) * inv;
  ob[1] = (s0.z + s1.z + s2.z + s3.z) * inv;
  ob[2] = (s0.w + s1.w + s2.w + s3.w) * inv;
}

// ---------------------------------------------------------------------------
extern "C" void kernel_launch(void* const* d_in, const int* in_sizes, int n_in,
                              void* d_out, int out_size, void* d_ws, size_t ws_size,
                              hipStream_t stream) {
  const float* src  = (const float*)d_in[0];
  const float* tgt  = (const float*)d_in[1];
  const float* sxyz = (const float*)d_in[2];
  const float* txyz = (const float*)d_in[3];
  const int* slens  = (const int*)d_in[4];
  const int* tlens  = (const int*)d_in[5];
  const float* Wq   = (const float*)d_in[6];
  const float* bq   = (const float*)d_in[7];
  const float* Wk   = (const float*)d_in[8];
  const float* bk   = (const float*)d_in[9];
  const float* Wc   = (const float*)d_in[10];
  const float* bc   = (const float*)d_in[11];
  float* out = (float*)d_out;

  char* ws = (char*)d_ws;
  size_t off = 0;
  auto carve = [&](size_t bytes) -> char* {
    char* p = ws + off;
    off += (bytes + 255) & ~(size_t)255;
    return p;
  };
  const size_t FEAT_BF  = (size_t)BAT * SEQ * DIM * 2;  // 16 MB bf16
  const size_t FEAT_FP8 = (size_t)BAT * SEQ * DIM;      // 8 MB fp8
  unsigned short* srcT = (unsigned short*)carve(FEAT_BF);
  unsigned short* tgtT = (unsigned short*)carve(FEAT_BF);
  unsigned char* Qsrc = (unsigned char*)carve(FEAT_FP8);
  unsigned char* Ktgt = (unsigned char*)carve(FEAT_FP8);
  unsigned char* Qtgt = (unsigned char*)carve(FEAT_FP8);
  unsigned char* Ksrc = (unsigned char*)carve(FEAT_FP8);
  unsigned short* Wqb  = (unsigned short*)carve((size_t)DIM * DIM * 2);
  unsigned short* Wkb  = (unsigned short*)carve((size_t)DIM * DIM * 2);
  float4* Vsrc = (float4*)carve((size_t)BAT * SEQ * 16);
  float4* Vtgt = (float4*)carve((size_t)BAT * SEQ * 16);
  // split-K partials (2 MB) aliased onto srcT (dead after k_proj).
  float4* part = (float4*)srcT;

  k_pack<<<dim3(4352, 2), 256, 0, stream>>>(src, tgt, Wc, bc, sxyz, txyz, Wq, Wk,
                                            srcT, tgtT, Vsrc, Vtgt, Wqb, Wkb, out);
  k_proj<<<dim3(2048), 256, 0, stream>>>(srcT, tgtT, Wqb, Wkb, bq, bk,
                                         Qsrc, Ktgt, Qtgt, Ksrc);
  k_attn<<<dim3(2048), 256, 0, stream>>>(Qsrc, Ktgt, Qtgt, Ksrc, Vsrc, Vtgt,
                                         slens, tlens, part);
  k_attn_reduce<<<dim3(128), 256, 0, stream>>>(part, out);
}

// Round 3
// 231.316 us; speedup vs baseline: 1.0738x; 1.0307x over previous
//
#include <hip/hip_runtime.h>

typedef __attribute__((ext_vector_type(8))) short short8;
typedef __attribute__((ext_vector_type(4))) short s16x4;
typedef __attribute__((ext_vector_type(4))) float f32x4;

#define SEQ 2048
#define BAT 8
#define DIM 512
#define RSQRT_D 0.044194173824159216f  // 1/sqrt(512)

__device__ __forceinline__ unsigned short f2bf(float x) {
  union { float f; unsigned u; } v; v.f = x;
  unsigned r = (v.u + 0x7FFFu + ((v.u >> 16) & 1u)) >> 16;  // RNE
  return (unsigned short)r;
}

__device__ __forceinline__ unsigned char f2fp8(float x) {
  return (unsigned char)(__builtin_amdgcn_cvt_pk_fp8_f32(x, x, 0, false) & 0xFF);
}

// async 16B global -> LDS. lds base wave-uniform; HW adds lane*16.
__device__ __forceinline__ void gload_lds16(const void* g, void* lds_base) {
  __builtin_amdgcn_global_load_lds(
      (const __attribute__((address_space(1))) unsigned int*)g,
      (__attribute__((address_space(3))) unsigned int*)lds_base,
      16, 0, 0);
}

// P.V via small bf16 MFMA (16x16x16: A=4 bf16, B=4 bf16, C=4 f32).
__device__ __forceinline__ f32x4 mfma_pv(s16x4 a, s16x4 b, f32x4 c) {
  asm("v_mfma_f32_16x16x16_bf16 %0, %1, %2, %0" : "+v"(c) : "v"(a), "v"(b));
  return c;
}

// ---------------------------------------------------------------------------
// Kernel 1: fused pack. blocks x<4096: transpose feats (S,B,D) f32 ->
// (B,S,D) bf16 + overlap dot (y = src/tgt). blocks >=4096: y==0 -> cast
// Wq/Wk -> bf16; y==1 -> pack xyz -> (B,S,4) f32. grid = (4352, 2).
// ---------------------------------------------------------------------------
__global__ __launch_bounds__(256) void k_pack(
    const float* __restrict__ src, const float* __restrict__ tgt,
    const float* __restrict__ Wc, const float* __restrict__ bc,
    const float* __restrict__ sxyz, const float* __restrict__ txyz,
    const float* __restrict__ Wq, const float* __restrict__ Wk,
    unsigned short* __restrict__ srcT, unsigned short* __restrict__ tgtT,
    float4* __restrict__ Vsrc, float4* __restrict__ Vtgt,
    unsigned short* __restrict__ Wqb, unsigned short* __restrict__ Wkb,
    float* __restrict__ out) {
  int which = blockIdx.y;
  if (blockIdx.x >= 4096) {
    int e = (blockIdx.x - 4096) * 256 + threadIdx.x;   // 0..65535
    if (which == 0) {
      int wsel = e >> 15, j = e & 32767;
      const float* wp = (wsel ? Wk : Wq) + (size_t)j * 8;
      unsigned short* o = wsel ? Wkb : Wqb;
      float4 f0 = *(const float4*)wp, f1 = *(const float4*)(wp + 4);
      uint4 pk;
      pk.x = (unsigned)f2bf(f0.x) | ((unsigned)f2bf(f0.y) << 16);
      pk.y = (unsigned)f2bf(f0.z) | ((unsigned)f2bf(f0.w) << 16);
      pk.z = (unsigned)f2bf(f1.x) | ((unsigned)f2bf(f1.y) << 16);
      pk.w = (unsigned)f2bf(f1.z) | ((unsigned)f2bf(f1.w) << 16);
      *(uint4*)(o + (size_t)j * 8) = pk;
    } else if (e < 32768) {
      int wsel = e >> 14, id = e & 16383;
      int s = id >> 3, b = id & 7;
      const float* xyz = (wsel ? txyz : sxyz) + (size_t)id * 3;
      float4 v = make_float4(xyz[0], xyz[1], xyz[2], 0.f);
      (wsel ? Vtgt : Vsrc)[b * SEQ + s] = v;
    }
    return;
  }
  int w = threadIdx.x >> 6, lane = threadIdx.x & 63;
  int row = blockIdx.x * 4 + w;            // row = s*B + b
  const float* in = (which ? tgt : src) + (size_t)row * DIM;
  unsigned short* T = which ? tgtT : srcT;
  int s = row >> 3, b = row & 7;

  const float4* in4 = (const float4*)in;
  float4 f0 = in4[lane * 2], f1 = in4[lane * 2 + 1];

  uint4 pk;
  pk.x = (unsigned)f2bf(f0.x) | ((unsigned)f2bf(f0.y) << 16);
  pk.y = (unsigned)f2bf(f0.z) | ((unsigned)f2bf(f0.w) << 16);
  pk.z = (unsigned)f2bf(f1.x) | ((unsigned)f2bf(f1.y) << 16);
  pk.w = (unsigned)f2bf(f1.z) | ((unsigned)f2bf(f1.w) << 16);
  *(uint4*)(T + ((size_t)(b * SEQ + s) * DIM + lane * 8)) = pk;

  const float4* wc4 = (const float4*)Wc;
  float4 w0 = wc4[lane * 2], w1 = wc4[lane * 2 + 1];
  float d = f0.x * w0.x + f0.y * w0.y + f0.z * w0.z + f0.w * w0.w +
            f1.x * w1.x + f1.y * w1.y + f1.z * w1.z + f1.w * w1.w;
  for (int o = 32; o; o >>= 1) d += __shfl_xor(d, o);
  if (lane == 0) {
    int base = which ? (SEQ * BAT * 6 + SEQ * BAT) : (SEQ * BAT * 6);
    out[base + row] = d + bc[0];
  }
}

// ---------------------------------------------------------------------------
// Kernel 2: projection GEMM, fp8-e4m3 output, UNSCALED (1/sqrt(D) in attn).
// Q linear; K with bank-free swizzle baked into the global byte layout:
//   byte (row,d) at row*512 + ((d>>3 ^ (row&15))<<3) + (d&7)
// XCD grouping: the 16 blocks (4 n x 4 z) sharing one m-tile are consecutive
// on one XCD (id%8) -> A-tile L2-fetched once per XCD; W L2-resident.
// grid = 2048 x 1D, block = 256.
// ---------------------------------------------------------------------------
__global__ __launch_bounds__(256) void k_proj(
    const unsigned short* __restrict__ srcT, const unsigned short* __restrict__ tgtT,
    const unsigned short* __restrict__ Wqb, const unsigned short* __restrict__ Wkb,
    const float* __restrict__ bq, const float* __restrict__ bk,
    unsigned char* __restrict__ Qsrc, unsigned char* __restrict__ Ktgt,
    unsigned char* __restrict__ Qtgt, unsigned char* __restrict__ Ksrc) {
  __shared__ __align__(16) char at[16384];   // 128 rows x 128B (64 bf16)
  __shared__ __align__(16) char bt[16384];
  int id = blockIdx.x;                 // 0..2047
  int x = id & 7, t = id >> 3;         // XCD = x (heuristic)
  int m = x * 16 + (t >> 4);           // 0..127, 16 consecutive blocks share m
  int inner = t & 15;
  int n = inner & 3, z = inner >> 2;
  bool isQ = (z == 0 || z == 2);
  const unsigned short* A = (z == 0 || z == 3) ? srcT : tgtT;
  const unsigned short* W = isQ ? Wqb : Wkb;
  const float* bias = isQ ? bq : bk;
  unsigned char* O = z == 0 ? Qsrc : z == 1 ? Ktgt : z == 2 ? Qtgt : Ksrc;

  int m0 = m * 128, n0 = n * 128;
  int tid = threadIdx.x, w = tid >> 6, lane = tid & 63;
  int ln = lane & 15, quad = lane >> 4;
  int moff = (w & 1) * 64, noff = (w >> 1) * 64;

  f32x4 acc[4][4];
  f32x4 zero = {0.f, 0.f, 0.f, 0.f};
  for (int mi = 0; mi < 4; ++mi)
    for (int ni = 0; ni < 4; ++ni) acc[mi][ni] = zero;

  for (int kb = 0; kb < DIM; kb += 64) {
    #pragma unroll
    for (int it = 0; it < 4; ++it) {
      int rbase = w * 32 + it * 8;
      int r = rbase + (lane >> 3);
      int c = (lane & 7) ^ (r & 7);
      gload_lds16(A + ((size_t)(m0 + r) * DIM + kb + c * 8), &at[rbase * 128]);
      gload_lds16(W + ((size_t)(n0 + r) * DIM + kb + c * 8), &bt[rbase * 128]);
    }
    __syncthreads();
    #pragma unroll
    for (int ks = 0; ks < 2; ++ks) {
      short8 afr[4], bfr[4];
      #pragma unroll
      for (int mi = 0; mi < 4; ++mi) {
        int r = moff + mi * 16 + ln;
        int p = (ks * 4 + quad) ^ (r & 7);
        afr[mi] = *(const short8*)(&at[r * 128 + p * 16]);
      }
      #pragma unroll
      for (int ni = 0; ni < 4; ++ni) {
        int r = noff + ni * 16 + ln;
        int p = (ks * 4 + quad) ^ (r & 7);
        bfr[ni] = *(const short8*)(&bt[r * 128 + p * 16]);
      }
      #pragma unroll
      for (int mi = 0; mi < 4; ++mi)
        #pragma unroll
        for (int ni = 0; ni < 4; ++ni)
          acc[mi][ni] = __builtin_amdgcn_mfma_f32_16x16x32_bf16(afr[mi], bfr[ni], acc[mi][ni], 0, 0, 0);
    }
    __syncthreads();
  }

  for (int ni = 0; ni < 4; ++ni) {
    int n_g = n0 + noff + ni * 16 + ln;
    float bv = bias[n_g];
    for (int mi = 0; mi < 4; ++mi) {
      int m_g = m0 + moff + mi * 16 + quad * 4;
      for (int r = 0; r < 4; ++r) {
        float v = acc[mi][ni][r] + bv;
        int row = m_g + r;
        size_t pos;
        if (isQ) pos = (size_t)row * DIM + n_g;
        else     pos = (size_t)row * DIM + ((((n_g >> 3) ^ (row & 15)) << 3) | (n_g & 7));
        O[pos] = f2fp8(v);
      }
    }
  }
}

// ---------------------------------------------------------------------------
// Kernel 3: flash attention, fp8 scores, split-K x4, no-max softmax, PV on
// the matrix pipe (swapped QK^T + bf16 16x16x16 PV MFMA, round-2 structure).
// v8: TWO Q-tiles per wave (q0 and q0+64). Every K b64 fragment read from LDS
// now feeds 2 independent MFMA chains -> LDS-read traffic and barrier count
// halve at constant MFMA work. grid 1024 (16 grp x 4 chunk x 16 qb), blk 256,
// 128 q / block. VGPR ~105 -> 4 waves/SIMD; 4 blocks/CU = 16 waves/CU (same
// resident-wave count as round 2's measured 45%).
// ---------------------------------------------------------------------------
__global__ __launch_bounds__(256) void k_attn(
    const unsigned char* __restrict__ Qsrc, const unsigned char* __restrict__ Ktgt,
    const unsigned char* __restrict__ Qtgt, const unsigned char* __restrict__ Ksrc,
    const float4* __restrict__ Vsrc, const float4* __restrict__ Vtgt,
    const int* __restrict__ src_lens, const int* __restrict__ tgt_lens,
    float4* __restrict__ part) {
  __shared__ __align__(16) char klds[16384];   // 32 keys x 512 B, swizzled
  __shared__ __align__(16) char vaug[4096];    // [grp=key/4][comp=4][j=4] bf16
  int id = blockIdx.x;                 // 0..1023
  int x = id & 7, j = id >> 3;         // XCD = x (heuristic)
  int group = (j >> 6) * 8 + x;        // 0..15 = dir*8+b, one XCD per 2 groups
  int dir = group >> 3, b = group & 7;
  int inner = j & 63;
  int chunk = inner >> 4, qb = inner & 15;

  const unsigned char* Q = dir ? Qtgt : Qsrc;
  const unsigned char* K = dir ? Ksrc : Ktgt;
  const float4* V = dir ? Vsrc : Vtgt;
  int len = (dir ? src_lens : tgt_lens)[b];
  int k0g = chunk * 512;
  int kend = min(len, k0g + 512);      // len >= 1792 so kend > k0g always
  int nblk = (kend - k0g + 31) >> 5;

  int tid = threadIdx.x, w = tid >> 6, lane = tid & 63;
  int ln = lane & 15, quad = lane >> 4;
  int q0 = qb * 128 + w * 16;          // tile A; tile B at q0+64

  // build Vaug: grp g holds bf16 Vaug[comp in {1,x,y,z}][key=g*4+j], with
  // invalid keys (>= len) zeroed -> exact masking through the PV MFMA.
  if (tid < 128) {
    int rem = kend - k0g;              // valid keys in this chunk
    const float4* vsrc = V + b * SEQ + k0g + tid * 4;
    float c[4][4];
    #pragma unroll
    for (int jj = 0; jj < 4; ++jj) {
      float4 vv = vsrc[jj];
      bool val = (tid * 4 + jj) < rem;
      c[0][jj] = val ? 1.f : 0.f;
      c[1][jj] = val ? vv.x : 0.f;
      c[2][jj] = val ? vv.y : 0.f;
      c[3][jj] = val ? vv.z : 0.f;
    }
    uint4 w0, w1;
    w0.x = (unsigned)f2bf(c[0][0]) | ((unsigned)f2bf(c[0][1]) << 16);
    w0.y = (unsigned)f2bf(c[0][2]) | ((unsigned)f2bf(c[0][3]) << 16);
    w0.z = (unsigned)f2bf(c[1][0]) | ((unsigned)f2bf(c[1][1]) << 16);
    w0.w = (unsigned)f2bf(c[1][2]) | ((unsigned)f2bf(c[1][3]) << 16);
    w1.x = (unsigned)f2bf(c[2][0]) | ((unsigned)f2bf(c[2][1]) << 16);
    w1.y = (unsigned)f2bf(c[2][2]) | ((unsigned)f2bf(c[2][3]) << 16);
    w1.z = (unsigned)f2bf(c[3][0]) | ((unsigned)f2bf(c[3][1]) << 16);
    w1.w = (unsigned)f2bf(c[3][2]) | ((unsigned)f2bf(c[3][3]) << 16);
    *(uint4*)(vaug + tid * 32) = w0;
    *(uint4*)(vaug + tid * 32 + 16) = w1;
  }

  // Q fp8 frags for both tiles: 2 x 16 x 8 B = 64 VGPRs.
  // Used as MFMA B-operand: B[k=quad*8+j][n=ln].
  long af[16], ag[16];
  {
    const unsigned char* qrowA = Q + (size_t)(b * SEQ + q0 + ln) * DIM + quad * 8;
    const unsigned char* qrowB = qrowA + (size_t)64 * DIM;
    #pragma unroll
    for (int kk = 0; kk < 16; ++kk) {
      af[kk] = *(const long*)(qrowA + kk * 32);
      ag[kk] = *(const long*)(qrowB + kk * 32);
    }
  }

  f32x4 accPV0 = {0.f, 0.f, 0.f, 0.f};  // rows(comp)=quad*4+r, col(q)=ln
  f32x4 accPV1 = {0.f, 0.f, 0.f, 0.f};
  const unsigned char* kchunk = K + (size_t)(b * SEQ + k0g) * DIM;

  for (int kb = 0; kb < nblk; ++kb) {
    // stage 32 keys x 512 B = 16 KB (identity copy; swizzle pre-baked).
    const unsigned char* kbase = kchunk + (size_t)kb * 32 * DIM;
    #pragma unroll
    for (int it = 0; it < 4; ++it) {
      int rp = w * 4 + it;             // 1 KB per slot
      gload_lds16(kbase + rp * 1024 + lane * 16, &klds[rp * 1024]);
    }
    __syncthreads();                   // stage complete (covers vaug build too)

    const char* krow0 = klds + ln * DIM;
    const char* krow1 = krow0 + 16 * DIM;

    // swapped QK^T: D[m=key sub][n=q=ln]; each K b64 feeds both Q-tiles.
    f32x4 acc0 = {0.f, 0.f, 0.f, 0.f}, acc1 = {0.f, 0.f, 0.f, 0.f};
    f32x4 acc2 = {0.f, 0.f, 0.f, 0.f}, acc3 = {0.f, 0.f, 0.f, 0.f};
    __builtin_amdgcn_s_setprio(1);
    #pragma unroll
    for (int kk = 0; kk < 16; ++kk) {
      int pos = (((kk * 4 + quad) ^ ln) << 3);  // swizzled 8B granule
      long b0 = *(const long*)(krow0 + pos);
      long b1 = *(const long*)(krow1 + pos);
      acc0 = __builtin_amdgcn_mfma_f32_16x16x32_fp8_fp8(b0, af[kk], acc0, 0, 0, 0);
      acc1 = __builtin_amdgcn_mfma_f32_16x16x32_fp8_fp8(b1, af[kk], acc1, 0, 0, 0);
      acc2 = __builtin_amdgcn_mfma_f32_16x16x32_fp8_fp8(b0, ag[kk], acc2, 0, 0, 0);
      acc3 = __builtin_amdgcn_mfma_f32_16x16x32_fp8_fp8(b1, ag[kk], acc3, 0, 0, 0);
    }
    __builtin_amdgcn_s_setprio(0);

    // softmax (no-max) -> bf16 P frags (B-layout of 16x16x16 mfma)
    union U { unsigned u[2]; s16x4 s; };
    U pA0, pA1, pB0, pB1;
    {
      float p0 = __expf(acc0[0] * RSQRT_D), p1 = __expf(acc0[1] * RSQRT_D);
      float p2 = __expf(acc0[2] * RSQRT_D), p3 = __expf(acc0[3] * RSQRT_D);
      asm("v_cvt_pk_bf16_f32 %0, %1, %2" : "=v"(pA0.u[0]) : "v"(p0), "v"(p1));
      asm("v_cvt_pk_bf16_f32 %0, %1, %2" : "=v"(pA0.u[1]) : "v"(p2), "v"(p3));
      float r0 = __expf(acc1[0] * RSQRT_D), r1 = __expf(acc1[1] * RSQRT_D);
      float r2 = __expf(acc1[2] * RSQRT_D), r3 = __expf(acc1[3] * RSQRT_D);
      asm("v_cvt_pk_bf16_f32 %0, %1, %2" : "=v"(pA1.u[0]) : "v"(r0), "v"(r1));
      asm("v_cvt_pk_bf16_f32 %0, %1, %2" : "=v"(pA1.u[1]) : "v"(r2), "v"(r3));
      float s0 = __expf(acc2[0] * RSQRT_D), s1 = __expf(acc2[1] * RSQRT_D);
      float s2 = __expf(acc2[2] * RSQRT_D), s3 = __expf(acc2[3] * RSQRT_D);
      asm("v_cvt_pk_bf16_f32 %0, %1, %2" : "=v"(pB0.u[0]) : "v"(s0), "v"(s1));
      asm("v_cvt_pk_bf16_f32 %0, %1, %2" : "=v"(pB0.u[1]) : "v"(s2), "v"(s3));
      float t0 = __expf(acc3[0] * RSQRT_D), t1 = __expf(acc3[1] * RSQRT_D);
      float t2 = __expf(acc3[2] * RSQRT_D), t3 = __expf(acc3[3] * RSQRT_D);
      asm("v_cvt_pk_bf16_f32 %0, %1, %2" : "=v"(pB1.u[0]) : "v"(t0), "v"(t1));
      asm("v_cvt_pk_bf16_f32 %0, %1, %2" : "=v"(pB1.u[1]) : "v"(t2), "v"(t3));
    }

    // Vaug A-frags: lane reads comp=ln&3 (rows>=4 of A are don't-care: only
    // D rows 0..3 are consumed). 4-lane same-address broadcast, conflict-free.
    int voff = kb * 256 + quad * 32 + (ln & 3) * 8;
    s16x4 va0 = *(const s16x4*)(vaug + voff);
    s16x4 va1 = *(const s16x4*)(vaug + voff + 128);
    accPV0 = mfma_pv(va0, pA0.s, accPV0);
    accPV0 = mfma_pv(va1, pA1.s, accPV0);
    accPV1 = mfma_pv(va0, pB0.s, accPV1);
    accPV1 = mfma_pv(va1, pB1.s, accPV1);

    __syncthreads();                   // all waves done reading klds
  }

  // quad0 lanes hold (l, Ox, Oy, Oz) for q = q0 + ln (tile A) and
  // q0 + 64 + ln (tile B). No shuffle reduce.
  if (quad == 0) {
    size_t base = ((size_t)(dir * BAT + b) * 4 + chunk) * SEQ;
    part[base + q0 + ln] =
        make_float4(accPV0[0], accPV0[1], accPV0[2], accPV0[3]);
    part[base + q0 + 64 + ln] =
        make_float4(accPV1[0], accPV1[1], accPV1[2], accPV1[3]);
  }
}

// ---------------------------------------------------------------------------
// Kernel 4: combine split-K partials.
// ---------------------------------------------------------------------------
__global__ __launch_bounds__(256) void k_attn_reduce(
    const float4* __restrict__ part, float* __restrict__ out) {
  int t = blockIdx.x * 256 + threadIdx.x;    // 0..32767
  int dir = t >> 14, rem = t & 16383, b = rem >> 11, q = rem & 2047;
  size_t base = ((size_t)(dir * BAT + b) * 4) * SEQ + q;
  float4 s0 = part[base];
  float4 s1 = part[base + SEQ];
  float4 s2 = part[base + 2 * SEQ];
  float4 s3 = part[base + 3 * SEQ];
  float inv = 1.f / (s0.x + s1.x + s2.x + s3.x);
  float* ob = out + (size_t)dir * (SEQ * BAT * 3) + ((size_t)q * BAT + b) * 3;
  ob[0] = (s0.y + s1.y + s2.y + s3.y) * inv;
  ob[1] = (s0.z + s1.z + s2.z + s3.z) * inv;
  ob[2] = (s0.w + s1.w + s2.w + s3.w) * inv;
}

// ---------------------------------------------------------------------------
extern "C" void kernel_launch(void* const* d_in, const int* in_sizes, int n_in,
                              void* d_out, int out_size, void* d_ws, size_t ws_size,
                              hipStream_t stream) {
  const float* src  = (const float*)d_in[0];
  const float* tgt  = (const float*)d_in[1];
  const float* sxyz = (const float*)d_in[2];
  const float* txyz = (const float*)d_in[3];
  const int* slens  = (const int*)d_in[4];
  const int* tlens  = (const int*)d_in[5];
  const float* Wq   = (const float*)d_in[6];
  const float* bq   = (const float*)d_in[7];
  const float* Wk   = (const float*)d_in[8];
  const float* bk   = (const float*)d_in[9];
  const float* Wc   = (const float*)d_in[10];
  const float* bc   = (const float*)d_in[11];
  float* out = (float*)d_out;

  char* ws = (char*)d_ws;
  size_t off = 0;
  auto carve = [&](size_t bytes) -> char* {
    char* p = ws + off;
    off += (bytes + 255) & ~(size_t)255;
    return p;
  };
  const size_t FEAT_BF  = (size_t)BAT * SEQ * DIM * 2;  // 16 MB bf16
  const size_t FEAT_FP8 = (size_t)BAT * SEQ * DIM;      // 8 MB fp8
  unsigned short* srcT = (unsigned short*)carve(FEAT_BF);
  unsigned short* tgtT = (unsigned short*)carve(FEAT_BF);
  unsigned char* Qsrc = (unsigned char*)carve(FEAT_FP8);
  unsigned char* Ktgt = (unsigned char*)carve(FEAT_FP8);
  unsigned char* Qtgt = (unsigned char*)carve(FEAT_FP8);
  unsigned char* Ksrc = (unsigned char*)carve(FEAT_FP8);
  unsigned short* Wqb  = (unsigned short*)carve((size_t)DIM * DIM * 2);
  unsigned short* Wkb  = (unsigned short*)carve((size_t)DIM * DIM * 2);
  float4* Vsrc = (float4*)carve((size_t)BAT * SEQ * 16);
  float4* Vtgt = (float4*)carve((size_t)BAT * SEQ * 16);
  // split-K partials (2 MB) aliased onto srcT (dead after k_proj).
  float4* part = (float4*)srcT;

  k_pack<<<dim3(4352, 2), 256, 0, stream>>>(src, tgt, Wc, bc, sxyz, txyz, Wq, Wk,
                                            srcT, tgtT, Vsrc, Vtgt, Wqb, Wkb, out);
  k_proj<<<dim3(2048), 256, 0, stream>>>(srcT, tgtT, Wqb, Wkb, bq, bk,
                                         Qsrc, Ktgt, Qtgt, Ksrc);
  k_attn<<<dim3(1024), 256, 0, stream>>>(Qsrc, Ktgt, Qtgt, Ksrc, Vsrc, Vtgt,
                                         slens, tlens, part);
  k_attn_reduce<<<dim3(128), 256, 0, stream>>>(part, out);
}

// Round 4
// 212.962 us; speedup vs baseline: 1.1663x; 1.0862x over previous
//
#include <hip/hip_runtime.h>

typedef __attribute__((ext_vector_type(8))) short short8;
typedef __attribute__((ext_vector_type(4))) short s16x4;
typedef __attribute__((ext_vector_type(4))) float f32x4;

#define SEQ 2048
#define BAT 8
#define DIM 512
#define RSQRT_D 0.044194173824159216f  // 1/sqrt(512)

__device__ __forceinline__ unsigned short f2bf(float x) {
  union { float f; unsigned u; } v; v.f = x;
  unsigned r = (v.u + 0x7FFFu + ((v.u >> 16) & 1u)) >> 16;  // RNE
  return (unsigned short)r;
}

__device__ __forceinline__ unsigned char f2fp8(float x) {
  return (unsigned char)(__builtin_amdgcn_cvt_pk_fp8_f32(x, x, 0, false) & 0xFF);
}

// async 16B global -> LDS. lds base wave-uniform; HW adds lane*16.
__device__ __forceinline__ void gload_lds16(const void* g, void* lds_base) {
  __builtin_amdgcn_global_load_lds(
      (const __attribute__((address_space(1))) unsigned int*)g,
      (__attribute__((address_space(3))) unsigned int*)lds_base,
      16, 0, 0);
}

// P.V via small bf16 MFMA (16x16x16: A=4 bf16, B=4 bf16, C=4 f32).
__device__ __forceinline__ f32x4 mfma_pv(s16x4 a, s16x4 b, f32x4 c) {
  asm("v_mfma_f32_16x16x16_bf16 %0, %1, %2, %0" : "+v"(c) : "v"(a), "v"(b));
  return c;
}

// ---------------------------------------------------------------------------
// Kernel 1: fused pack. blocks x<4096: transpose feats (S,B,D) f32 ->
// (B,S,D) bf16 + overlap dot (y = src/tgt). blocks >=4096: y==0 -> cast
// Wq/Wk -> bf16; y==1 -> pack xyz -> (B,S,4) f32. grid = (4352, 2).
// ---------------------------------------------------------------------------
__global__ __launch_bounds__(256) void k_pack(
    const float* __restrict__ src, const float* __restrict__ tgt,
    const float* __restrict__ Wc, const float* __restrict__ bc,
    const float* __restrict__ sxyz, const float* __restrict__ txyz,
    const float* __restrict__ Wq, const float* __restrict__ Wk,
    unsigned short* __restrict__ srcT, unsigned short* __restrict__ tgtT,
    float4* __restrict__ Vsrc, float4* __restrict__ Vtgt,
    unsigned short* __restrict__ Wqb, unsigned short* __restrict__ Wkb,
    float* __restrict__ out) {
  int which = blockIdx.y;
  if (blockIdx.x >= 4096) {
    int e = (blockIdx.x - 4096) * 256 + threadIdx.x;   // 0..65535
    if (which == 0) {
      int wsel = e >> 15, j = e & 32767;
      const float* wp = (wsel ? Wk : Wq) + (size_t)j * 8;
      unsigned short* o = wsel ? Wkb : Wqb;
      float4 f0 = *(const float4*)wp, f1 = *(const float4*)(wp + 4);
      uint4 pk;
      pk.x = (unsigned)f2bf(f0.x) | ((unsigned)f2bf(f0.y) << 16);
      pk.y = (unsigned)f2bf(f0.z) | ((unsigned)f2bf(f0.w) << 16);
      pk.z = (unsigned)f2bf(f1.x) | ((unsigned)f2bf(f1.y) << 16);
      pk.w = (unsigned)f2bf(f1.z) | ((unsigned)f2bf(f1.w) << 16);
      *(uint4*)(o + (size_t)j * 8) = pk;
    } else if (e < 32768) {
      int wsel = e >> 14, id = e & 16383;
      int s = id >> 3, b = id & 7;
      const float* xyz = (wsel ? txyz : sxyz) + (size_t)id * 3;
      float4 v = make_float4(xyz[0], xyz[1], xyz[2], 0.f);
      (wsel ? Vtgt : Vsrc)[b * SEQ + s] = v;
    }
    return;
  }
  int w = threadIdx.x >> 6, lane = threadIdx.x & 63;
  int row = blockIdx.x * 4 + w;            // row = s*B + b
  const float* in = (which ? tgt : src) + (size_t)row * DIM;
  unsigned short* T = which ? tgtT : srcT;
  int s = row >> 3, b = row & 7;

  const float4* in4 = (const float4*)in;
  float4 f0 = in4[lane * 2], f1 = in4[lane * 2 + 1];

  uint4 pk;
  pk.x = (unsigned)f2bf(f0.x) | ((unsigned)f2bf(f0.y) << 16);
  pk.y = (unsigned)f2bf(f0.z) | ((unsigned)f2bf(f0.w) << 16);
  pk.z = (unsigned)f2bf(f1.x) | ((unsigned)f2bf(f1.y) << 16);
  pk.w = (unsigned)f2bf(f1.z) | ((unsigned)f2bf(f1.w) << 16);
  *(uint4*)(T + ((size_t)(b * SEQ + s) * DIM + lane * 8)) = pk;

  const float4* wc4 = (const float4*)Wc;
  float4 w0 = wc4[lane * 2], w1 = wc4[lane * 2 + 1];
  float d = f0.x * w0.x + f0.y * w0.y + f0.z * w0.z + f0.w * w0.w +
            f1.x * w1.x + f1.y * w1.y + f1.z * w1.z + f1.w * w1.w;
  for (int o = 32; o; o >>= 1) d += __shfl_xor(d, o);
  if (lane == 0) {
    int base = which ? (SEQ * BAT * 6 + SEQ * BAT) : (SEQ * BAT * 6);
    out[base + row] = d + bc[0];
  }
}

// ---------------------------------------------------------------------------
// Kernel 2: projection GEMM, fp8-e4m3 output, UNSCALED (1/sqrt(D) in attn).
// v9: merged z-pairs. One 512-thread block stages ONE A-tile (128x64/step)
// plus BOTH Wq and Wk tiles; waves 0-3 compute the Q output, waves 4-7 the
// K output. Per K-step: 48 KB staged + 2 barriers for 64 MFMA (was 64 KB +
// 4 barriers across the two blocks this replaces). Epilogue uses SWAPPED
// mfma operands -> D[n][m]: each lane's 4 acc regs = 4 consecutive n for one
// row -> 2x cvt_pk_fp8 + ONE u32 store (was 4 byte-stores + 4 cvts).
// K output keeps the attn bank-free swizzle baked into the global layout:
//   byte (row,d) at row*512 + ((d>>3 ^ (row&15))<<3) + (d&7)
// grid = 1024 (XCD-grouped: 8 consecutive blocks = 4n x 2ap share m-strip),
// block = 512. LDS 48 KB -> 3 blocks/CU = 24 waves.
// ---------------------------------------------------------------------------
__global__ __launch_bounds__(512) void k_proj(
    const unsigned short* __restrict__ srcT, const unsigned short* __restrict__ tgtT,
    const unsigned short* __restrict__ Wqb, const unsigned short* __restrict__ Wkb,
    const float* __restrict__ bq, const float* __restrict__ bk,
    unsigned char* __restrict__ Qsrc, unsigned char* __restrict__ Ktgt,
    unsigned char* __restrict__ Qtgt, unsigned char* __restrict__ Ksrc) {
  __shared__ __align__(16) char at[16384];    // A tile: 128 rows x 128 B
  __shared__ __align__(16) char wqt[16384];   // Wq tile
  __shared__ __align__(16) char wkt[16384];   // Wk tile
  int id = blockIdx.x;                 // 0..1023
  int x = id & 7, t = id >> 3;         // XCD = x (heuristic)
  int m = x * 16 + (t >> 3);           // 0..127; 8 consecutive blocks share m
  int inner = t & 7;
  int n = inner & 3, ap = inner >> 2;  // ap: 0 = srcT, 1 = tgtT
  const unsigned short* A = ap ? tgtT : srcT;

  int m0 = m * 128, n0 = n * 128;
  int tid = threadIdx.x, w = tid >> 6, lane = tid & 63;
  int ln = lane & 15, quad = lane >> 4;
  int grp = w >> 2, wl = w & 3;        // grp 0 = Q-output, 1 = K-output
  int moff = (wl & 1) * 64, noff = (wl >> 1) * 64;
  const float* bias = grp ? bk : bq;
  unsigned char* O = grp ? (ap ? Ktgt : Ksrc) : (ap ? Qtgt : Qsrc);

  f32x4 acc[4][4];                     // [mi][ni]; D[n=quad*4+r][m=ln]
  f32x4 zero = {0.f, 0.f, 0.f, 0.f};
  for (int mi = 0; mi < 4; ++mi)
    for (int ni = 0; ni < 4; ++ni) acc[mi][ni] = zero;

  for (int kb = 0; kb < DIM; kb += 64) {
    // stage 48 slots x 1 KB: slots 0-15 = A, 16-31 = Wq, 32-47 = Wk.
    #pragma unroll
    for (int it = 0; it < 6; ++it) {
      int s = w * 6 + it;              // 0..47, each exactly once
      int tile = s >> 4, within = s & 15;
      int rbase = within * 8;
      int r = rbase + (lane >> 3);
      int c = (lane & 7) ^ (r & 7);
      const unsigned short* g =
          (tile == 0 ? A + (size_t)(m0 + r) * DIM
                     : (tile == 1 ? Wqb : Wkb) + (size_t)(n0 + r) * DIM) +
          kb + c * 8;
      char* dst = (tile == 0 ? at : tile == 1 ? wqt : wkt) + rbase * 128;
      gload_lds16(g, dst);
    }
    __syncthreads();
    const char* bt = grp ? wkt : wqt;
    #pragma unroll
    for (int ks = 0; ks < 2; ++ks) {
      short8 afr[4], bfr[4];
      #pragma unroll
      for (int mi = 0; mi < 4; ++mi) {
        int r = moff + mi * 16 + ln;
        int p = (ks * 4 + quad) ^ (r & 7);
        afr[mi] = *(const short8*)(&at[r * 128 + p * 16]);
      }
      #pragma unroll
      for (int ni = 0; ni < 4; ++ni) {
        int r = noff + ni * 16 + ln;
        int p = (ks * 4 + quad) ^ (r & 7);
        bfr[ni] = *(const short8*)(&bt[r * 128 + p * 16]);
      }
      // swapped operands: D rows = n (quad*4+r), cols = m (ln).
      #pragma unroll
      for (int mi = 0; mi < 4; ++mi)
        #pragma unroll
        for (int ni = 0; ni < 4; ++ni)
          acc[mi][ni] = __builtin_amdgcn_mfma_f32_16x16x32_bf16(bfr[ni], afr[mi], acc[mi][ni], 0, 0, 0);
    }
    __syncthreads();
  }

  // epilogue: per (mi,ni) lane owns row m0+moff+mi*16+ln, 4 consecutive n.
  bool isQ = (grp == 0);
  #pragma unroll
  for (int ni = 0; ni < 4; ++ni) {
    int n_b = n0 + noff + ni * 16 + quad * 4;
    float4 bv = *(const float4*)(bias + n_b);
    #pragma unroll
    for (int mi = 0; mi < 4; ++mi) {
      int row = m0 + moff + mi * 16 + ln;
      int u;
      u = __builtin_amdgcn_cvt_pk_fp8_f32(acc[mi][ni][0] + bv.x,
                                          acc[mi][ni][1] + bv.y, 0, false);
      u = __builtin_amdgcn_cvt_pk_fp8_f32(acc[mi][ni][2] + bv.z,
                                          acc[mi][ni][3] + bv.w, u, true);
      size_t pos;
      if (isQ) pos = (size_t)row * DIM + n_b;
      else     pos = (size_t)row * DIM + ((((n_b >> 3) ^ (row & 15)) << 3) | (n_b & 7));
      *(unsigned*)(O + pos) = (unsigned)u;
    }
  }
}

// ---------------------------------------------------------------------------
// Kernel 3: flash attention, fp8 scores, split-K x4, no-max softmax, PV on
// the matrix pipe (swapped QK^T + bf16 16x16x16 PV MFMA), TWO Q-tiles/wave.
// grid 1024, blk 256. (round-3 structure, unchanged)
// ---------------------------------------------------------------------------
__global__ __launch_bounds__(256) void k_attn(
    const unsigned char* __restrict__ Qsrc, const unsigned char* __restrict__ Ktgt,
    const unsigned char* __restrict__ Qtgt, const unsigned char* __restrict__ Ksrc,
    const float4* __restrict__ Vsrc, const float4* __restrict__ Vtgt,
    const int* __restrict__ src_lens, const int* __restrict__ tgt_lens,
    float4* __restrict__ part) {
  __shared__ __align__(16) char klds[16384];   // 32 keys x 512 B, swizzled
  __shared__ __align__(16) char vaug[4096];    // [grp=key/4][comp=4][j=4] bf16
  int id = blockIdx.x;                 // 0..1023
  int x = id & 7, j = id >> 3;         // XCD = x (heuristic)
  int group = (j >> 6) * 8 + x;        // 0..15 = dir*8+b, one XCD per 2 groups
  int dir = group >> 3, b = group & 7;
  int inner = j & 63;
  int chunk = inner >> 4, qb = inner & 15;

  const unsigned char* Q = dir ? Qtgt : Qsrc;
  const unsigned char* K = dir ? Ksrc : Ktgt;
  const float4* V = dir ? Vsrc : Vtgt;
  int len = (dir ? src_lens : tgt_lens)[b];
  int k0g = chunk * 512;
  int kend = min(len, k0g + 512);      // len >= 1792 so kend > k0g always
  int nblk = (kend - k0g + 31) >> 5;

  int tid = threadIdx.x, w = tid >> 6, lane = tid & 63;
  int ln = lane & 15, quad = lane >> 4;
  int q0 = qb * 128 + w * 16;          // tile A; tile B at q0+64

  // build Vaug: grp g holds bf16 Vaug[comp in {1,x,y,z}][key=g*4+j], with
  // invalid keys (>= len) zeroed -> exact masking through the PV MFMA.
  if (tid < 128) {
    int rem = kend - k0g;              // valid keys in this chunk
    const float4* vsrc = V + b * SEQ + k0g + tid * 4;
    float c[4][4];
    #pragma unroll
    for (int jj = 0; jj < 4; ++jj) {
      float4 vv = vsrc[jj];
      bool val = (tid * 4 + jj) < rem;
      c[0][jj] = val ? 1.f : 0.f;
      c[1][jj] = val ? vv.x : 0.f;
      c[2][jj] = val ? vv.y : 0.f;
      c[3][jj] = val ? vv.z : 0.f;
    }
    uint4 w0, w1;
    w0.x = (unsigned)f2bf(c[0][0]) | ((unsigned)f2bf(c[0][1]) << 16);
    w0.y = (unsigned)f2bf(c[0][2]) | ((unsigned)f2bf(c[0][3]) << 16);
    w0.z = (unsigned)f2bf(c[1][0]) | ((unsigned)f2bf(c[1][1]) << 16);
    w0.w = (unsigned)f2bf(c[1][2]) | ((unsigned)f2bf(c[1][3]) << 16);
    w1.x = (unsigned)f2bf(c[2][0]) | ((unsigned)f2bf(c[2][1]) << 16);
    w1.y = (unsigned)f2bf(c[2][2]) | ((unsigned)f2bf(c[2][3]) << 16);
    w1.z = (unsigned)f2bf(c[3][0]) | ((unsigned)f2bf(c[3][1]) << 16);
    w1.w = (unsigned)f2bf(c[3][2]) | ((unsigned)f2bf(c[3][3]) << 16);
    *(uint4*)(vaug + tid * 32) = w0;
    *(uint4*)(vaug + tid * 32 + 16) = w1;
  }

  // Q fp8 frags for both tiles: 2 x 16 x 8 B = 64 VGPRs.
  // Used as MFMA B-operand: B[k=quad*8+j][n=ln].
  long af[16], ag[16];
  {
    const unsigned char* qrowA = Q + (size_t)(b * SEQ + q0 + ln) * DIM + quad * 8;
    const unsigned char* qrowB = qrowA + (size_t)64 * DIM;
    #pragma unroll
    for (int kk = 0; kk < 16; ++kk) {
      af[kk] = *(const long*)(qrowA + kk * 32);
      ag[kk] = *(const long*)(qrowB + kk * 32);
    }
  }

  f32x4 accPV0 = {0.f, 0.f, 0.f, 0.f};  // rows(comp)=quad*4+r, col(q)=ln
  f32x4 accPV1 = {0.f, 0.f, 0.f, 0.f};
  const unsigned char* kchunk = K + (size_t)(b * SEQ + k0g) * DIM;

  for (int kb = 0; kb < nblk; ++kb) {
    // stage 32 keys x 512 B = 16 KB (identity copy; swizzle pre-baked).
    const unsigned char* kbase = kchunk + (size_t)kb * 32 * DIM;
    #pragma unroll
    for (int it = 0; it < 4; ++it) {
      int rp = w * 4 + it;             // 1 KB per slot
      gload_lds16(kbase + rp * 1024 + lane * 16, &klds[rp * 1024]);
    }
    __syncthreads();                   // stage complete (covers vaug build too)

    const char* krow0 = klds + ln * DIM;
    const char* krow1 = krow0 + 16 * DIM;

    // swapped QK^T: D[m=key sub][n=q=ln]; each K b64 feeds both Q-tiles.
    f32x4 acc0 = {0.f, 0.f, 0.f, 0.f}, acc1 = {0.f, 0.f, 0.f, 0.f};
    f32x4 acc2 = {0.f, 0.f, 0.f, 0.f}, acc3 = {0.f, 0.f, 0.f, 0.f};
    __builtin_amdgcn_s_setprio(1);
    #pragma unroll
    for (int kk = 0; kk < 16; ++kk) {
      int pos = (((kk * 4 + quad) ^ ln) << 3);  // swizzled 8B granule
      long b0 = *(const long*)(krow0 + pos);
      long b1 = *(const long*)(krow1 + pos);
      acc0 = __builtin_amdgcn_mfma_f32_16x16x32_fp8_fp8(b0, af[kk], acc0, 0, 0, 0);
      acc1 = __builtin_amdgcn_mfma_f32_16x16x32_fp8_fp8(b1, af[kk], acc1, 0, 0, 0);
      acc2 = __builtin_amdgcn_mfma_f32_16x16x32_fp8_fp8(b0, ag[kk], acc2, 0, 0, 0);
      acc3 = __builtin_amdgcn_mfma_f32_16x16x32_fp8_fp8(b1, ag[kk], acc3, 0, 0, 0);
    }
    __builtin_amdgcn_s_setprio(0);

    // softmax (no-max) -> bf16 P frags (B-layout of 16x16x16 mfma)
    union U { unsigned u[2]; s16x4 s; };
    U pA0, pA1, pB0, pB1;
    {
      float p0 = __expf(acc0[0] * RSQRT_D), p1 = __expf(acc0[1] * RSQRT_D);
      float p2 = __expf(acc0[2] * RSQRT_D), p3 = __expf(acc0[3] * RSQRT_D);
      asm("v_cvt_pk_bf16_f32 %0, %1, %2" : "=v"(pA0.u[0]) : "v"(p0), "v"(p1));
      asm("v_cvt_pk_bf16_f32 %0, %1, %2" : "=v"(pA0.u[1]) : "v"(p2), "v"(p3));
      float r0 = __expf(acc1[0] * RSQRT_D), r1 = __expf(acc1[1] * RSQRT_D);
      float r2 = __expf(acc1[2] * RSQRT_D), r3 = __expf(acc1[3] * RSQRT_D);
      asm("v_cvt_pk_bf16_f32 %0, %1, %2" : "=v"(pA1.u[0]) : "v"(r0), "v"(r1));
      asm("v_cvt_pk_bf16_f32 %0, %1, %2" : "=v"(pA1.u[1]) : "v"(r2), "v"(r3));
      float s0 = __expf(acc2[0] * RSQRT_D), s1 = __expf(acc2[1] * RSQRT_D);
      float s2 = __expf(acc2[2] * RSQRT_D), s3 = __expf(acc2[3] * RSQRT_D);
      asm("v_cvt_pk_bf16_f32 %0, %1, %2" : "=v"(pB0.u[0]) : "v"(s0), "v"(s1));
      asm("v_cvt_pk_bf16_f32 %0, %1, %2" : "=v"(pB0.u[1]) : "v"(s2), "v"(s3));
      float t0 = __expf(acc3[0] * RSQRT_D), t1 = __expf(acc3[1] * RSQRT_D);
      float t2 = __expf(acc3[2] * RSQRT_D), t3 = __expf(acc3[3] * RSQRT_D);
      asm("v_cvt_pk_bf16_f32 %0, %1, %2" : "=v"(pB1.u[0]) : "v"(t0), "v"(t1));
      asm("v_cvt_pk_bf16_f32 %0, %1, %2" : "=v"(pB1.u[1]) : "v"(t2), "v"(t3));
    }

    // Vaug A-frags: lane reads comp=ln&3 (rows>=4 of A are don't-care: only
    // D rows 0..3 are consumed). 4-lane same-address broadcast, conflict-free.
    int voff = kb * 256 + quad * 32 + (ln & 3) * 8;
    s16x4 va0 = *(const s16x4*)(vaug + voff);
    s16x4 va1 = *(const s16x4*)(vaug + voff + 128);
    accPV0 = mfma_pv(va0, pA0.s, accPV0);
    accPV0 = mfma_pv(va1, pA1.s, accPV0);
    accPV1 = mfma_pv(va0, pB0.s, accPV1);
    accPV1 = mfma_pv(va1, pB1.s, accPV1);

    __syncthreads();                   // all waves done reading klds
  }

  // quad0 lanes hold (l, Ox, Oy, Oz) for q = q0 + ln (tile A) and
  // q0 + 64 + ln (tile B). No shuffle reduce.
  if (quad == 0) {
    size_t base = ((size_t)(dir * BAT + b) * 4 + chunk) * SEQ;
    part[base + q0 + ln] =
        make_float4(accPV0[0], accPV0[1], accPV0[2], accPV0[3]);
    part[base + q0 + 64 + ln] =
        make_float4(accPV1[0], accPV1[1], accPV1[2], accPV1[3]);
  }
}

// ---------------------------------------------------------------------------
// Kernel 4: combine split-K partials.
// ---------------------------------------------------------------------------
__global__ __launch_bounds__(256) void k_attn_reduce(
    const float4* __restrict__ part, float* __restrict__ out) {
  int t = blockIdx.x * 256 + threadIdx.x;    // 0..32767
  int dir = t >> 14, rem = t & 16383, b = rem >> 11, q = rem & 2047;
  size_t base = ((size_t)(dir * BAT + b) * 4) * SEQ + q;
  float4 s0 = part[base];
  float4 s1 = part[base + SEQ];
  float4 s2 = part[base + 2 * SEQ];
  float4 s3 = part[base + 3 * SEQ];
  float inv = 1.f / (s0.x + s1.x + s2.x + s3.x);
  float* ob = out + (size_t)dir * (SEQ * BAT * 3) + ((size_t)q * BAT + b) * 3;
  ob[0] = (s0.y + s1.y + s2.y + s3.y) * inv;
  ob[1] = (s0.z + s1.z + s2.z + s3.z) * inv;
  ob[2] = (s0.w + s1.w + s2.w + s3.w) * inv;
}

// ---------------------------------------------------------------------------
extern "C" void kernel_launch(void* const* d_in, const int* in_sizes, int n_in,
                              void* d_out, int out_size, void* d_ws, size_t ws_size,
                              hipStream_t stream) {
  const float* src  = (const float*)d_in[0];
  const float* tgt  = (const float*)d_in[1];
  const float* sxyz = (const float*)d_in[2];
  const float* txyz = (const float*)d_in[3];
  const int* slens  = (const int*)d_in[4];
  const int* tlens  = (const int*)d_in[5];
  const float* Wq   = (const float*)d_in[6];
  const float* bq   = (const float*)d_in[7];
  const float* Wk   = (const float*)d_in[8];
  const float* bk   = (const float*)d_in[9];
  const float* Wc   = (const float*)d_in[10];
  const float* bc   = (const float*)d_in[11];
  float* out = (float*)d_out;

  char* ws = (char*)d_ws;
  size_t off = 0;
  auto carve = [&](size_t bytes) -> char* {
    char* p = ws + off;
    off += (bytes + 255) & ~(size_t)255;
    return p;
  };
  const size_t FEAT_BF  = (size_t)BAT * SEQ * DIM * 2;  // 16 MB bf16
  const size_t FEAT_FP8 = (size_t)BAT * SEQ * DIM;      // 8 MB fp8
  unsigned short* srcT = (unsigned short*)carve(FEAT_BF);
  unsigned short* tgtT = (unsigned short*)carve(FEAT_BF);
  unsigned char* Qsrc = (unsigned char*)carve(FEAT_FP8);
  unsigned char* Ktgt = (unsigned char*)carve(FEAT_FP8);
  unsigned char* Qtgt = (unsigned char*)carve(FEAT_FP8);
  unsigned char* Ksrc = (unsigned char*)carve(FEAT_FP8);
  unsigned short* Wqb  = (unsigned short*)carve((size_t)DIM * DIM * 2);
  unsigned short* Wkb  = (unsigned short*)carve((size_t)DIM * DIM * 2);
  float4* Vsrc = (float4*)carve((size_t)BAT * SEQ * 16);
  float4* Vtgt = (float4*)carve((size_t)BAT * SEQ * 16);
  // split-K partials (2 MB) aliased onto srcT (dead after k_proj).
  float4* part = (float4*)srcT;

  k_pack<<<dim3(4352, 2), 256, 0, stream>>>(src, tgt, Wc, bc, sxyz, txyz, Wq, Wk,
                                            srcT, tgtT, Vsrc, Vtgt, Wqb, Wkb, out);
  k_proj<<<dim3(1024), 512, 0, stream>>>(srcT, tgtT, Wqb, Wkb, bq, bk,
                                         Qsrc, Ktgt, Qtgt, Ksrc);
  k_attn<<<dim3(1024), 256, 0, stream>>>(Qsrc, Ktgt, Qtgt, Ksrc, Vsrc, Vtgt,
                                         slens, tlens, part);
  k_attn_reduce<<<dim3(128), 256, 0, stream>>>(part, out);
}

// Round 7
// 212.043 us; speedup vs baseline: 1.1714x; 1.0043x over previous
//
#include <hip/hip_runtime.h>

typedef __attribute__((ext_vector_type(8))) short short8;
typedef __attribute__((ext_vector_type(4))) short s16x4;
typedef __attribute__((ext_vector_type(4))) float f32x4;

#define SEQ 2048
#define BAT 8
#define DIM 512
#define RSQRT_D 0.044194173824159216f  // 1/sqrt(512)

__device__ __forceinline__ unsigned short f2bf(float x) {
  union { float f; unsigned u; } v; v.f = x;
  unsigned r = (v.u + 0x7FFFu + ((v.u >> 16) & 1u)) >> 16;  // RNE
  return (unsigned short)r;
}

__device__ __forceinline__ unsigned char f2fp8(float x) {
  return (unsigned char)(__builtin_amdgcn_cvt_pk_fp8_f32(x, x, 0, false) & 0xFF);
}

// async 16B global -> LDS. lds base wave-uniform; HW adds lane*16.
__device__ __forceinline__ void gload_lds16(const void* g, void* lds_base) {
  __builtin_amdgcn_global_load_lds(
      (const __attribute__((address_space(1))) unsigned int*)g,
      (__attribute__((address_space(3))) unsigned int*)lds_base,
      16, 0, 0);
}

// P.V via small bf16 MFMA (16x16x16: A=4 bf16, B=4 bf16, C=4 f32).
__device__ __forceinline__ f32x4 mfma_pv(s16x4 a, s16x4 b, f32x4 c) {
  asm("v_mfma_f32_16x16x16_bf16 %0, %1, %2, %0" : "+v"(c) : "v"(a), "v"(b));
  return c;
}

// ---------------------------------------------------------------------------
// Kernel 1: fused pack. blocks x<4096: transpose feats (S,B,D) f32 ->
// (B,S,D) bf16 + overlap dot (y = src/tgt). blocks >=4096: y==0 -> cast
// Wq/Wk -> bf16; y==1 -> pack xyz -> (B,S,4) f32. grid = (4352, 2).
// ---------------------------------------------------------------------------
__global__ __launch_bounds__(256) void k_pack(
    const float* __restrict__ src, const float* __restrict__ tgt,
    const float* __restrict__ Wc, const float* __restrict__ bc,
    const float* __restrict__ sxyz, const float* __restrict__ txyz,
    const float* __restrict__ Wq, const float* __restrict__ Wk,
    unsigned short* __restrict__ srcT, unsigned short* __restrict__ tgtT,
    float4* __restrict__ Vsrc, float4* __restrict__ Vtgt,
    unsigned short* __restrict__ Wqb, unsigned short* __restrict__ Wkb,
    float* __restrict__ out) {
  int which = blockIdx.y;
  if (blockIdx.x >= 4096) {
    int e = (blockIdx.x - 4096) * 256 + threadIdx.x;   // 0..65535
    if (which == 0) {
      int wsel = e >> 15, j = e & 32767;
      const float* wp = (wsel ? Wk : Wq) + (size_t)j * 8;
      unsigned short* o = wsel ? Wkb : Wqb;
      float4 f0 = *(const float4*)wp, f1 = *(const float4*)(wp + 4);
      uint4 pk;
      pk.x = (unsigned)f2bf(f0.x) | ((unsigned)f2bf(f0.y) << 16);
      pk.y = (unsigned)f2bf(f0.z) | ((unsigned)f2bf(f0.w) << 16);
      pk.z = (unsigned)f2bf(f1.x) | ((unsigned)f2bf(f1.y) << 16);
      pk.w = (unsigned)f2bf(f1.z) | ((unsigned)f2bf(f1.w) << 16);
      *(uint4*)(o + (size_t)j * 8) = pk;
    } else if (e < 32768) {
      int wsel = e >> 14, id = e & 16383;
      int s = id >> 3, b = id & 7;
      const float* xyz = (wsel ? txyz : sxyz) + (size_t)id * 3;
      float4 v = make_float4(xyz[0], xyz[1], xyz[2], 0.f);
      (wsel ? Vtgt : Vsrc)[b * SEQ + s] = v;
    }
    return;
  }
  int w = threadIdx.x >> 6, lane = threadIdx.x & 63;
  int row = blockIdx.x * 4 + w;            // row = s*B + b
  const float* in = (which ? tgt : src) + (size_t)row * DIM;
  unsigned short* T = which ? tgtT : srcT;
  int s = row >> 3, b = row & 7;

  const float4* in4 = (const float4*)in;
  float4 f0 = in4[lane * 2], f1 = in4[lane * 2 + 1];

  uint4 pk;
  pk.x = (unsigned)f2bf(f0.x) | ((unsigned)f2bf(f0.y) << 16);
  pk.y = (unsigned)f2bf(f0.z) | ((unsigned)f2bf(f0.w) << 16);
  pk.z = (unsigned)f2bf(f1.x) | ((unsigned)f2bf(f1.y) << 16);
  pk.w = (unsigned)f2bf(f1.z) | ((unsigned)f2bf(f1.w) << 16);
  *(uint4*)(T + ((size_t)(b * SEQ + s) * DIM + lane * 8)) = pk;

  const float4* wc4 = (const float4*)Wc;
  float4 w0 = wc4[lane * 2], w1 = wc4[lane * 2 + 1];
  float d = f0.x * w0.x + f0.y * w0.y + f0.z * w0.z + f0.w * w0.w +
            f1.x * w1.x + f1.y * w1.y + f1.z * w1.z + f1.w * w1.w;
  for (int o = 32; o; o >>= 1) d += __shfl_xor(d, o);
  if (lane == 0) {
    int base = which ? (SEQ * BAT * 6 + SEQ * BAT) : (SEQ * BAT * 6);
    out[base + row] = d + bc[0];
  }
}

// ---------------------------------------------------------------------------
// Kernel 2: projection GEMM, fp8-e4m3 output, UNSCALED (1/sqrt(D) in attn).
// v9 structure: merged z-pairs, 512-thread block, shared A + Wq + Wk tiles,
// swapped-operand epilogue (u32 fp8 stores). grid 1024, block 512.
// K output bank-free swizzle baked into the global byte layout:
//   byte (row,d) at row*512 + ((d>>3 ^ (row&15))<<3) + (d&7)
// ---------------------------------------------------------------------------
__global__ __launch_bounds__(512) void k_proj(
    const unsigned short* __restrict__ srcT, const unsigned short* __restrict__ tgtT,
    const unsigned short* __restrict__ Wqb, const unsigned short* __restrict__ Wkb,
    const float* __restrict__ bq, const float* __restrict__ bk,
    unsigned char* __restrict__ Qsrc, unsigned char* __restrict__ Ktgt,
    unsigned char* __restrict__ Qtgt, unsigned char* __restrict__ Ksrc) {
  __shared__ __align__(16) char at[16384];    // A tile: 128 rows x 128 B
  __shared__ __align__(16) char wqt[16384];   // Wq tile
  __shared__ __align__(16) char wkt[16384];   // Wk tile
  int id = blockIdx.x;                 // 0..1023
  int x = id & 7, t = id >> 3;         // XCD = x (heuristic)
  int m = x * 16 + (t >> 3);           // 0..127; 8 consecutive blocks share m
  int inner = t & 7;
  int n = inner & 3, ap = inner >> 2;  // ap: 0 = srcT, 1 = tgtT
  const unsigned short* A = ap ? tgtT : srcT;

  int m0 = m * 128, n0 = n * 128;
  int tid = threadIdx.x, w = tid >> 6, lane = tid & 63;
  int ln = lane & 15, quad = lane >> 4;
  int grp = w >> 2, wl = w & 3;        // grp 0 = Q-output, 1 = K-output
  int moff = (wl & 1) * 64, noff = (wl >> 1) * 64;
  const float* bias = grp ? bk : bq;
  unsigned char* O = grp ? (ap ? Ktgt : Ksrc) : (ap ? Qtgt : Qsrc);

  f32x4 acc[4][4];                     // [mi][ni]; D[n=quad*4+r][m=ln]
  f32x4 zero = {0.f, 0.f, 0.f, 0.f};
  for (int mi = 0; mi < 4; ++mi)
    for (int ni = 0; ni < 4; ++ni) acc[mi][ni] = zero;

  for (int kb = 0; kb < DIM; kb += 64) {
    // stage 48 slots x 1 KB: slots 0-15 = A, 16-31 = Wq, 32-47 = Wk.
    #pragma unroll
    for (int it = 0; it < 6; ++it) {
      int s = w * 6 + it;              // 0..47, each exactly once
      int tile = s >> 4, within = s & 15;
      int rbase = within * 8;
      int r = rbase + (lane >> 3);
      int c = (lane & 7) ^ (r & 7);
      const unsigned short* g =
          (tile == 0 ? A + (size_t)(m0 + r) * DIM
                     : (tile == 1 ? Wqb : Wkb) + (size_t)(n0 + r) * DIM) +
          kb + c * 8;
      char* dst = (tile == 0 ? at : tile == 1 ? wqt : wkt) + rbase * 128;
      gload_lds16(g, dst);
    }
    __syncthreads();
    const char* bt = grp ? wkt : wqt;
    #pragma unroll
    for (int ks = 0; ks < 2; ++ks) {
      short8 afr[4], bfr[4];
      #pragma unroll
      for (int mi = 0; mi < 4; ++mi) {
        int r = moff + mi * 16 + ln;
        int p = (ks * 4 + quad) ^ (r & 7);
        afr[mi] = *(const short8*)(&at[r * 128 + p * 16]);
      }
      #pragma unroll
      for (int ni = 0; ni < 4; ++ni) {
        int r = noff + ni * 16 + ln;
        int p = (ks * 4 + quad) ^ (r & 7);
        bfr[ni] = *(const short8*)(&bt[r * 128 + p * 16]);
      }
      // swapped operands: D rows = n (quad*4+r), cols = m (ln).
      #pragma unroll
      for (int mi = 0; mi < 4; ++mi)
        #pragma unroll
        for (int ni = 0; ni < 4; ++ni)
          acc[mi][ni] = __builtin_amdgcn_mfma_f32_16x16x32_bf16(bfr[ni], afr[mi], acc[mi][ni], 0, 0, 0);
    }
    __syncthreads();
  }

  // epilogue: per (mi,ni) lane owns row m0+moff+mi*16+ln, 4 consecutive n.
  bool isQ = (grp == 0);
  #pragma unroll
  for (int ni = 0; ni < 4; ++ni) {
    int n_b = n0 + noff + ni * 16 + quad * 4;
    float4 bv = *(const float4*)(bias + n_b);
    #pragma unroll
    for (int mi = 0; mi < 4; ++mi) {
      int row = m0 + moff + mi * 16 + ln;
      int u;
      u = __builtin_amdgcn_cvt_pk_fp8_f32(acc[mi][ni][0] + bv.x,
                                          acc[mi][ni][1] + bv.y, 0, false);
      u = __builtin_amdgcn_cvt_pk_fp8_f32(acc[mi][ni][2] + bv.z,
                                          acc[mi][ni][3] + bv.w, u, true);
      size_t pos;
      if (isQ) pos = (size_t)row * DIM + n_b;
      else     pos = (size_t)row * DIM + ((((n_b >> 3) ^ (row & 15)) << 3) | (n_b & 7));
      *(unsigned*)(O + pos) = (unsigned)u;
    }
  }
}

// ---------------------------------------------------------------------------
// Kernel 3: flash attention, fp8 scores, split-K x4, no-max softmax, PV on
// the matrix pipe (swapped QK^T + bf16 16x16x16 PV MFMA), TWO Q-tiles/wave.
// grid 1024, blk 256. (round-4 verified structure; MX-MFMA and split-K x8
// variants both failed correctness — reverted bit-exact.)
// ---------------------------------------------------------------------------
__global__ __launch_bounds__(256) void k_attn(
    const unsigned char* __restrict__ Qsrc, const unsigned char* __restrict__ Ktgt,
    const unsigned char* __restrict__ Qtgt, const unsigned char* __restrict__ Ksrc,
    const float4* __restrict__ Vsrc, const float4* __restrict__ Vtgt,
    const int* __restrict__ src_lens, const int* __restrict__ tgt_lens,
    float4* __restrict__ part) {
  __shared__ __align__(16) char klds[16384];   // 32 keys x 512 B, swizzled
  __shared__ __align__(16) char vaug[4096];    // [grp=key/4][comp=4][j=4] bf16
  int id = blockIdx.x;                 // 0..1023
  int x = id & 7, j = id >> 3;         // XCD = x (heuristic)
  int group = (j >> 6) * 8 + x;        // 0..15 = dir*8+b, one XCD per 2 groups
  int dir = group >> 3, b = group & 7;
  int inner = j & 63;
  int chunk = inner >> 4, qb = inner & 15;

  const unsigned char* Q = dir ? Qtgt : Qsrc;
  const unsigned char* K = dir ? Ksrc : Ktgt;
  const float4* V = dir ? Vsrc : Vtgt;
  int len = (dir ? src_lens : tgt_lens)[b];
  int k0g = chunk * 512;
  int kend = min(len, k0g + 512);      // len >= 1792 so kend > k0g always
  int nblk = (kend - k0g + 31) >> 5;

  int tid = threadIdx.x, w = tid >> 6, lane = tid & 63;
  int ln = lane & 15, quad = lane >> 4;
  int q0 = qb * 128 + w * 16;          // tile A; tile B at q0+64

  // build Vaug: grp g holds bf16 Vaug[comp in {1,x,y,z}][key=g*4+j], with
  // invalid keys (>= len) zeroed -> exact masking through the PV MFMA.
  if (tid < 128) {
    int rem = kend - k0g;              // valid keys in this chunk
    const float4* vsrc = V + b * SEQ + k0g + tid * 4;
    float c[4][4];
    #pragma unroll
    for (int jj = 0; jj < 4; ++jj) {
      float4 vv = vsrc[jj];
      bool val = (tid * 4 + jj) < rem;
      c[0][jj] = val ? 1.f : 0.f;
      c[1][jj] = val ? vv.x : 0.f;
      c[2][jj] = val ? vv.y : 0.f;
      c[3][jj] = val ? vv.z : 0.f;
    }
    uint4 w0, w1;
    w0.x = (unsigned)f2bf(c[0][0]) | ((unsigned)f2bf(c[0][1]) << 16);
    w0.y = (unsigned)f2bf(c[0][2]) | ((unsigned)f2bf(c[0][3]) << 16);
    w0.z = (unsigned)f2bf(c[1][0]) | ((unsigned)f2bf(c[1][1]) << 16);
    w0.w = (unsigned)f2bf(c[1][2]) | ((unsigned)f2bf(c[1][3]) << 16);
    w1.x = (unsigned)f2bf(c[2][0]) | ((unsigned)f2bf(c[2][1]) << 16);
    w1.y = (unsigned)f2bf(c[2][2]) | ((unsigned)f2bf(c[2][3]) << 16);
    w1.z = (unsigned)f2bf(c[3][0]) | ((unsigned)f2bf(c[3][1]) << 16);
    w1.w = (unsigned)f2bf(c[3][2]) | ((unsigned)f2bf(c[3][3]) << 16);
    *(uint4*)(vaug + tid * 32) = w0;
    *(uint4*)(vaug + tid * 32 + 16) = w1;
  }

  // Q fp8 frags for both tiles: 2 x 16 x 8 B = 64 VGPRs.
  // Used as MFMA B-operand: B[k=quad*8+j][n=ln].
  long af[16], ag[16];
  {
    const unsigned char* qrowA = Q + (size_t)(b * SEQ + q0 + ln) * DIM + quad * 8;
    const unsigned char* qrowB = qrowA + (size_t)64 * DIM;
    #pragma unroll
    for (int kk = 0; kk < 16; ++kk) {
      af[kk] = *(const long*)(qrowA + kk * 32);
      ag[kk] = *(const long*)(qrowB + kk * 32);
    }
  }

  f32x4 accPV0 = {0.f, 0.f, 0.f, 0.f};  // rows(comp)=quad*4+r, col(q)=ln
  f32x4 accPV1 = {0.f, 0.f, 0.f, 0.f};
  const unsigned char* kchunk = K + (size_t)(b * SEQ + k0g) * DIM;

  for (int kb = 0; kb < nblk; ++kb) {
    // stage 32 keys x 512 B = 16 KB (identity copy; swizzle pre-baked).
    const unsigned char* kbase = kchunk + (size_t)kb * 32 * DIM;
    #pragma unroll
    for (int it = 0; it < 4; ++it) {
      int rp = w * 4 + it;             // 1 KB per slot
      gload_lds16(kbase + rp * 1024 + lane * 16, &klds[rp * 1024]);
    }
    __syncthreads();                   // stage complete (covers vaug build too)

    const char* krow0 = klds + ln * DIM;
    const char* krow1 = krow0 + 16 * DIM;

    // swapped QK^T: D[m=key sub][n=q=ln]; each K b64 feeds both Q-tiles.
    f32x4 acc0 = {0.f, 0.f, 0.f, 0.f}, acc1 = {0.f, 0.f, 0.f, 0.f};
    f32x4 acc2 = {0.f, 0.f, 0.f, 0.f}, acc3 = {0.f, 0.f, 0.f, 0.f};
    __builtin_amdgcn_s_setprio(1);
    #pragma unroll
    for (int kk = 0; kk < 16; ++kk) {
      int pos = (((kk * 4 + quad) ^ ln) << 3);  // swizzled 8B granule
      long b0 = *(const long*)(krow0 + pos);
      long b1 = *(const long*)(krow1 + pos);
      acc0 = __builtin_amdgcn_mfma_f32_16x16x32_fp8_fp8(b0, af[kk], acc0, 0, 0, 0);
      acc1 = __builtin_amdgcn_mfma_f32_16x16x32_fp8_fp8(b1, af[kk], acc1, 0, 0, 0);
      acc2 = __builtin_amdgcn_mfma_f32_16x16x32_fp8_fp8(b0, ag[kk], acc2, 0, 0, 0);
      acc3 = __builtin_amdgcn_mfma_f32_16x16x32_fp8_fp8(b1, ag[kk], acc3, 0, 0, 0);
    }
    __builtin_amdgcn_s_setprio(0);

    // softmax (no-max) -> bf16 P frags (B-layout of 16x16x16 mfma)
    union U { unsigned u[2]; s16x4 s; };
    U pA0, pA1, pB0, pB1;
    {
      float p0 = __expf(acc0[0] * RSQRT_D), p1 = __expf(acc0[1] * RSQRT_D);
      float p2 = __expf(acc0[2] * RSQRT_D), p3 = __expf(acc0[3] * RSQRT_D);
      asm("v_cvt_pk_bf16_f32 %0, %1, %2" : "=v"(pA0.u[0]) : "v"(p0), "v"(p1));
      asm("v_cvt_pk_bf16_f32 %0, %1, %2" : "=v"(pA0.u[1]) : "v"(p2), "v"(p3));
      float r0 = __expf(acc1[0] * RSQRT_D), r1 = __expf(acc1[1] * RSQRT_D);
      float r2 = __expf(acc1[2] * RSQRT_D), r3 = __expf(acc1[3] * RSQRT_D);
      asm("v_cvt_pk_bf16_f32 %0, %1, %2" : "=v"(pA1.u[0]) : "v"(r0), "v"(r1));
      asm("v_cvt_pk_bf16_f32 %0, %1, %2" : "=v"(pA1.u[1]) : "v"(r2), "v"(r3));
      float s0 = __expf(acc2[0] * RSQRT_D), s1 = __expf(acc2[1] * RSQRT_D);
      float s2 = __expf(acc2[2] * RSQRT_D), s3 = __expf(acc2[3] * RSQRT_D);
      asm("v_cvt_pk_bf16_f32 %0, %1, %2" : "=v"(pB0.u[0]) : "v"(s0), "v"(s1));
      asm("v_cvt_pk_bf16_f32 %0, %1, %2" : "=v"(pB0.u[1]) : "v"(s2), "v"(s3));
      float t0 = __expf(acc3[0] * RSQRT_D), t1 = __expf(acc3[1] * RSQRT_D);
      float t2 = __expf(acc3[2] * RSQRT_D), t3 = __expf(acc3[3] * RSQRT_D);
      asm("v_cvt_pk_bf16_f32 %0, %1, %2" : "=v"(pB1.u[0]) : "v"(t0), "v"(t1));
      asm("v_cvt_pk_bf16_f32 %0, %1, %2" : "=v"(pB1.u[1]) : "v"(t2), "v"(t3));
    }

    // Vaug A-frags: lane reads comp=ln&3 (rows>=4 of A are don't-care: only
    // D rows 0..3 are consumed). 4-lane same-address broadcast, conflict-free.
    int voff = kb * 256 + quad * 32 + (ln & 3) * 8;
    s16x4 va0 = *(const s16x4*)(vaug + voff);
    s16x4 va1 = *(const s16x4*)(vaug + voff + 128);
    accPV0 = mfma_pv(va0, pA0.s, accPV0);
    accPV0 = mfma_pv(va1, pA1.s, accPV0);
    accPV1 = mfma_pv(va0, pB0.s, accPV1);
    accPV1 = mfma_pv(va1, pB1.s, accPV1);

    __syncthreads();                   // all waves done reading klds
  }

  // quad0 lanes hold (l, Ox, Oy, Oz) for q = q0 + ln (tile A) and
  // q0 + 64 + ln (tile B). No shuffle reduce.
  if (quad == 0) {
    size_t base = ((size_t)(dir * BAT + b) * 4 + chunk) * SEQ;
    part[base + q0 + ln] =
        make_float4(accPV0[0], accPV0[1], accPV0[2], accPV0[3]);
    part[base + q0 + 64 + ln] =
        make_float4(accPV1[0], accPV1[1], accPV1[2], accPV1[3]);
  }
}

// ---------------------------------------------------------------------------
// Kernel 4: combine split-K partials.
// ---------------------------------------------------------------------------
__global__ __launch_bounds__(256) void k_attn_reduce(
    const float4* __restrict__ part, float* __restrict__ out) {
  int t = blockIdx.x * 256 + threadIdx.x;    // 0..32767
  int dir = t >> 14, rem = t & 16383, b = rem >> 11, q = rem & 2047;
  size_t base = ((size_t)(dir * BAT + b) * 4) * SEQ + q;
  float4 s0 = part[base];
  float4 s1 = part[base + SEQ];
  float4 s2 = part[base + 2 * SEQ];
  float4 s3 = part[base + 3 * SEQ];
  float inv = 1.f / (s0.x + s1.x + s2.x + s3.x);
  float* ob = out + (size_t)dir * (SEQ * BAT * 3) + ((size_t)q * BAT + b) * 3;
  ob[0] = (s0.y + s1.y + s2.y + s3.y) * inv;
  ob[1] = (s0.z + s1.z + s2.z + s3.z) * inv;
  ob[2] = (s0.w + s1.w + s2.w + s3.w) * inv;
}

// ---------------------------------------------------------------------------
extern "C" void kernel_launch(void* const* d_in, const int* in_sizes, int n_in,
                              void* d_out, int out_size, void* d_ws, size_t ws_size,
                              hipStream_t stream) {
  const float* src  = (const float*)d_in[0];
  const float* tgt  = (const float*)d_in[1];
  const float* sxyz = (const float*)d_in[2];
  const float* txyz = (const float*)d_in[3];
  const int* slens  = (const int*)d_in[4];
  const int* tlens  = (const int*)d_in[5];
  const float* Wq   = (const float*)d_in[6];
  const float* bq   = (const float*)d_in[7];
  const float* Wk   = (const float*)d_in[8];
  const float* bk   = (const float*)d_in[9];
  const float* Wc   = (const float*)d_in[10];
  const float* bc   = (const float*)d_in[11];
  float* out = (float*)d_out;

  char* ws = (char*)d_ws;
  size_t off = 0;
  auto carve = [&](size_t bytes) -> char* {
    char* p = ws + off;
    off += (bytes + 255) & ~(size_t)255;
    return p;
  };
  const size_t FEAT_BF  = (size_t)BAT * SEQ * DIM * 2;  // 16 MB bf16
  const size_t FEAT_FP8 = (size_t)BAT * SEQ * DIM;      // 8 MB fp8
  unsigned short* srcT = (unsigned short*)carve(FEAT_BF);
  unsigned short* tgtT = (unsigned short*)carve(FEAT_BF);
  unsigned char* Qsrc = (unsigned char*)carve(FEAT_FP8);
  unsigned char* Ktgt = (unsigned char*)carve(FEAT_FP8);
  unsigned char* Qtgt = (unsigned char*)carve(FEAT_FP8);
  unsigned char* Ksrc = (unsigned char*)carve(FEAT_FP8);
  unsigned short* Wqb  = (unsigned short*)carve((size_t)DIM * DIM * 2);
  unsigned short* Wkb  = (unsigned short*)carve((size_t)DIM * DIM * 2);
  float4* Vsrc = (float4*)carve((size_t)BAT * SEQ * 16);
  float4* Vtgt = (float4*)carve((size_t)BAT * SEQ * 16);
  // split-K partials (2 MB) aliased onto srcT (dead after k_proj).
  float4* part = (float4*)srcT;

  k_pack<<<dim3(4352, 2), 256, 0, stream>>>(src, tgt, Wc, bc, sxyz, txyz, Wq, Wk,
                                            srcT, tgtT, Vsrc, Vtgt, Wqb, Wkb, out);
  k_proj<<<dim3(1024), 512, 0, stream>>>(srcT, tgtT, Wqb, Wkb, bq, bk,
                                         Qsrc, Ktgt, Qtgt, Ksrc);
  k_attn<<<dim3(1024), 256, 0, stream>>>(Qsrc, Ktgt, Qtgt, Ksrc, Vsrc, Vtgt,
                                         slens, tlens, part);
  k_attn_reduce<<<dim3(128), 256, 0, stream>>>(part, out);
}